// Round 13
// baseline (2539.220 us; speedup 1.0000x reference)
//
#include <hip/hip_runtime.h>
#include <hip/hip_bf16.h>
#include <hip/hip_fp16.h>

// ---------------------------------------------------------------------------
// BiLSTM (N=512, D_IN=300, H=256) + pairwise 3-layer MLP (4H->H->H->50)
// + log_softmax, on MI355X.
//
//   lstm (round-13): r10's MFMA recurrence (best so far, 862us) with ONE
//   change: the 2 LDS-streamed A-tiles per wave now stream from a GLOBAL
//   fragment-packed buffer (prep2, aliases dead WihT space). 16 KB/CU/step
//   -> L1-resident; loads ride the idle VMEM pipe. DS drops 34->18
//   instr/wave/step; the DS pipe (3.3k cy) stops being critical and the
//   MFMA floor (~2.5k cy) takes over. LDS shrinks to 5 KB static.
// ---------------------------------------------------------------------------

typedef _Float16 f16x2 __attribute__((ext_vector_type(2)));
typedef _Float16 f16x8 __attribute__((ext_vector_type(8)));
typedef float    f32x4  __attribute__((ext_vector_type(4)));
typedef float    f32x16 __attribute__((ext_vector_type(16)));

__device__ __forceinline__ float sigf(float x){ return 1.f/(1.f + __expf(-x)); }

// ------------------------------ prep ---------------------------------------
__global__ __launch_bounds__(256) void prep_kernel(
    const float* __restrict__ Wih_f, const float* __restrict__ Wih_b,
    const float* __restrict__ W1,    const float* __restrict__ W2,
    const float* __restrict__ W3,    const float* __restrict__ b3,
    float* __restrict__ WihT, float* __restrict__ W1aT, float* __restrict__ W1bT,
    _Float16* __restrict__ W2h, _Float16* __restrict__ W3h,
    float* __restrict__ b3p)
{
  int idx = blockIdx.x * 256 + threadIdx.x;
  if (idx < 614400){                     // WihT[d][c][r] = Wih_d[r][c]
    int d = idx / 307200, r2 = idx % 307200;
    int cc = r2 / 1024, rr = r2 % 1024;
    const float* src = d ? Wih_b : Wih_f;
    WihT[idx] = src[rr*300 + cc];
    return;
  }
  idx -= 614400;
  if (idx < 262144){                     // W1aT[c][p]=W1[p][c]; W1bT[c][p]=W1[p][512+c]
    int sel = idx / 131072, r2 = idx % 131072;
    int cc = r2 / 256, pp = r2 % 256;
    float v = W1[pp*1024 + sel*512 + cc];
    (sel ? W1bT : W1aT)[r2] = v;
    return;
  }
  idx -= 262144;
  if (idx < 65536){ W2h[idx] = (_Float16)W2[idx]; return; }
  idx -= 65536;
  if (idx < 16384){                      // W3h padded to [64][256]
    int n = idx >> 8, k = idx & 255;
    W3h[idx] = (n < 50) ? (_Float16)W3[n*256 + k] : (_Float16)0.f;
    return;
  }
  idx -= 16384;
  if (idx < 64){ b3p[idx] = (idx < 50) ? b3[idx] : 0.f; return; }
}

// ------------------------------ prep2 ---------------------------------------
// Packs lstm A-fragments for tiles 6,7 of each wave into Wg (global).
// Layout: byte_off = ((dir*8+w)*16 + tt*8 + c)*1024 + lane*16.
// Runs AFTER xb_kernel (Wg aliases the then-dead WihT region).
__global__ __launch_bounds__(256) void prep2_kernel(
    const float* __restrict__ Whh_f, const float* __restrict__ Whh_b,
    _Float16* __restrict__ Wg)
{
  const int idx = blockIdx.x * 256 + threadIdx.x;    // 16384 items
  const int lane = idx & 63;
  const int c    = (idx >> 6) & 7;
  const int tt   = (idx >> 9) & 1;
  const int w    = (idx >> 10) & 7;
  const int dir  = (idx >> 13) & 1;
  const int lg = lane >> 4, lr = lane & 15;
  const int rowp = (w*8 + 6 + tt)*16 + lr;
  const int orow = (rowp & 3)*256 + (rowp >> 2);     // row' = unit*4+gate
  const float* src = (dir ? Whh_b : Whh_f) + (size_t)orow*256 + lg*8 + c*32;
  float4 v0 = *(const float4*)(src);
  float4 v1 = *(const float4*)(src + 4);
  f16x8 o;
  o[0]=(_Float16)v0.x; o[1]=(_Float16)v0.y; o[2]=(_Float16)v0.z; o[3]=(_Float16)v0.w;
  o[4]=(_Float16)v1.x; o[5]=(_Float16)v1.y; o[6]=(_Float16)v1.z; o[7]=(_Float16)v1.w;
  *(f16x8*)(Wg + (size_t)idx*8) = o;
}

// ------------------------------ xb ------------------------------------------
// Writes PERMUTED layout: xb'[t][unit*4 + gate]  (float4 per unit, coalesced)
__global__ __launch_bounds__(256) void xb_kernel(
    const float* __restrict__ x, const float* __restrict__ WihT,
    const float* __restrict__ bih_f, const float* __restrict__ bhh_f,
    const float* __restrict__ bih_b, const float* __restrict__ bhh_b,
    float* __restrict__ xb)
{
  const int tid = threadIdx.x;
  const int dir = blockIdx.x >> 7;
  const int t0  = (blockIdx.x & 127) * 4;
  __shared__ float xs[4][304];
  #pragma unroll
  for (int tt = 0; tt < 4; ++tt)
    if (tid < 75) ((float4*)xs[tt])[tid] = ((const float4*)(x + (size_t)(t0+tt)*300))[tid];
  __syncthreads();
  const float* W = WihT + dir*307200;
  float acc[4][4];
  #pragma unroll
  for (int r = 0; r < 4; ++r){
    #pragma unroll
    for (int tt = 0; tt < 4; ++tt) acc[r][tt] = 0.f;
  }
  for (int c = 0; c < 300; ++c){
    float x0 = xs[0][c], x1 = xs[1][c], x2 = xs[2][c], x3 = xs[3][c];
    #pragma unroll
    for (int r = 0; r < 4; ++r){
      float wv = W[c*1024 + r*256 + tid];
      acc[r][0] += wv*x0; acc[r][1] += wv*x1; acc[r][2] += wv*x2; acc[r][3] += wv*x3;
    }
  }
  const float* bih = dir ? bih_b : bih_f;
  const float* bhh = dir ? bhh_b : bhh_f;
  float bias[4];
  #pragma unroll
  for (int r = 0; r < 4; ++r) bias[r] = bih[r*256 + tid] + bhh[r*256 + tid];
  float* xbd = xb + (size_t)dir*512*1024;
  #pragma unroll
  for (int tt = 0; tt < 4; ++tt){
    float4 v;
    v.x = acc[0][tt] + bias[0];
    v.y = acc[1][tt] + bias[1];
    v.z = acc[2][tt] + bias[2];
    v.w = acc[3][tt] + bias[3];
    *(float4*)(xbd + (size_t)(t0+tt)*1024 + tid*4) = v;
  }
}

// ------------------------------ lstm ----------------------------------------
#define MFMA16(A, B, C) __builtin_amdgcn_mfma_f32_16x16x32_f16((A), (B), (C), 0, 0, 0)

__global__ __launch_bounds__(512)
__attribute__((amdgpu_waves_per_eu(2, 2)))
void lstm_kernel(
    const float* __restrict__ Whh_f, const float* __restrict__ Whh_b,
    const float* __restrict__ xb, float* __restrict__ outcat,
    const _Float16* __restrict__ Wg)
{
  __shared__ float    gl[1024];          // gate results, unit-major
  __shared__ _Float16 hbuf[2][256];

  const int tid = threadIdx.x;
  const int dir = blockIdx.x;
  const int w   = tid >> 6;
  const int l   = tid & 63;
  const int lg  = l >> 4;      // k-group (0..3)
  const int lr  = l & 15;      // row within tile
  const float* Whh = dir ? Whh_b : Whh_f;

  // per-lane base into the packed global A-frag buffer (tiles 6,7)
  const char* gp = (const char*)Wg + (size_t)(dir*8 + w)*16384 + l*16;

  // ---- init: tiles 0..5 as register fragments (AGPR-friendly; MFMA-native)
  f16x8 wreg[48];
  #pragma unroll
  for (int tt = 0; tt < 6; ++tt){
    const int rowp = (w*8 + tt)*16 + lr;
    const int orow = (rowp & 3)*256 + (rowp >> 2);
    const float* src = Whh + (size_t)orow*256 + lg*8;
    #pragma unroll
    for (int c = 0; c < 8; ++c){
      float4 v0 = *(const float4*)(src + c*32);
      float4 v1 = *(const float4*)(src + c*32 + 4);
      f16x8 o;
      o[0]=(_Float16)v0.x; o[1]=(_Float16)v0.y; o[2]=(_Float16)v0.z; o[3]=(_Float16)v0.w;
      o[4]=(_Float16)v1.x; o[5]=(_Float16)v1.y; o[6]=(_Float16)v1.z; o[7]=(_Float16)v1.w;
      wreg[tt*8 + c] = o;
    }
  }
  if (tid < 32) ((f16x8*)hbuf[0])[tid] = (f16x8)(_Float16)0.f;   // h_{-1} = 0
  __syncthreads();

  const float* xbd = xb + (size_t)dir*512*1024;
  float cst = 0.f;                         // c-state (threads < 256)

  for (int it = 0; it < 512; ++it){
    const int t = dir ? (511 - it) : it;
    float4 xb4;
    if (tid < 256) xb4 = *(const float4*)(xbd + (size_t)t*1024 + tid*4);

    // B fragments: h broadcast to all cols; lane slot j <- h[c*32 + lg*8 + j]
    const _Float16* hsrc = hbuf[it & 1] + lg*8;
    f16x8 hf[8];
    #pragma unroll
    for (int c = 0; c < 8; ++c) hf[c] = *(const f16x8*)(hsrc + c*32);

    const bool owner = (lr == 0);

    // issue tile-6 loads early (VMEM, L1-hit after step 0)
    f16x8 g[8];
    #pragma unroll
    for (int c = 0; c < 8; ++c) g[c] = *(const f16x8*)(gp + c*1024);

    { // tiles 0,1 (reg-only) -- covers tile-6 load latency
      f32x4 a0 = {0.f,0.f,0.f,0.f}, a1 = {0.f,0.f,0.f,0.f};
      #pragma unroll
      for (int c = 0; c < 8; ++c){
        a0 = MFMA16(wreg[0*8+c], hf[c], a0);
        a1 = MFMA16(wreg[1*8+c], hf[c], a1);
      }
      if (owner){
        *(f32x4*)(gl + ((w*8+0)*4 + lg)*4) = a0;
        *(f32x4*)(gl + ((w*8+1)*4 + lg)*4) = a1;
      }
    }
    { // tiles 4,6 (reg + global-streamed)
      f32x4 a0 = {0.f,0.f,0.f,0.f}, a1 = {0.f,0.f,0.f,0.f};
      #pragma unroll
      for (int c = 0; c < 8; ++c){
        a0 = MFMA16(wreg[4*8+c], hf[c], a0);
        a1 = MFMA16(g[c], hf[c], a1);
      }
      if (owner){
        *(f32x4*)(gl + ((w*8+4)*4 + lg)*4) = a0;
        *(f32x4*)(gl + ((w*8+6)*4 + lg)*4) = a1;
      }
    }
    // issue tile-7 loads
    #pragma unroll
    for (int c = 0; c < 8; ++c) g[c] = *(const f16x8*)(gp + 8192 + c*1024);

    { // tiles 2,3 (reg-only) -- covers tile-7 load latency
      f32x4 a0 = {0.f,0.f,0.f,0.f}, a1 = {0.f,0.f,0.f,0.f};
      #pragma unroll
      for (int c = 0; c < 8; ++c){
        a0 = MFMA16(wreg[2*8+c], hf[c], a0);
        a1 = MFMA16(wreg[3*8+c], hf[c], a1);
      }
      if (owner){
        *(f32x4*)(gl + ((w*8+2)*4 + lg)*4) = a0;
        *(f32x4*)(gl + ((w*8+3)*4 + lg)*4) = a1;
      }
    }
    { // tiles 5,7 (reg + global-streamed)
      f32x4 a0 = {0.f,0.f,0.f,0.f}, a1 = {0.f,0.f,0.f,0.f};
      #pragma unroll
      for (int c = 0; c < 8; ++c){
        a0 = MFMA16(wreg[5*8+c], hf[c], a0);
        a1 = MFMA16(g[c], hf[c], a1);
      }
      if (owner){
        *(f32x4*)(gl + ((w*8+5)*4 + lg)*4) = a0;
        *(f32x4*)(gl + ((w*8+7)*4 + lg)*4) = a1;
      }
    }
    __syncthreads();                       // gl complete

    if (tid < 256){
      f32x4 g4 = *(const f32x4*)(gl + tid*4);
      const float gi = g4[0] + xb4.x;
      const float gf = g4[1] + xb4.y;
      const float gg = g4[2] + xb4.z;
      const float go = g4[3] + xb4.w;
      const float iv = sigf(gi);
      const float fv = sigf(gf);
      const float gv = fmaf(sigf(2.f*gg), 2.f, -1.f);    // tanh
      const float ov = sigf(go);
      cst = fmaf(fv, cst, iv*gv);
      const float h = ov * fmaf(sigf(2.f*cst), 2.f, -1.f);
      hbuf[(it + 1) & 1][tid] = (_Float16)h;
      outcat[(size_t)t*512 + dir*256 + tid] = h;
    }
    __syncthreads();                       // hbuf ready for next step
  }
}

// ------------------------------ ab ------------------------------------------
__global__ __launch_bounds__(512) void ab_kernel(
    const float* __restrict__ outcat, const float* __restrict__ W1aT,
    const float* __restrict__ W1bT,  const float* __restrict__ b1,
    float* __restrict__ aP, float* __restrict__ bP)
{
  __shared__ float orow[512];
  const int tid = threadIdx.x;
  const int i = blockIdx.x;
  if (tid < 128) ((float4*)orow)[tid] = ((const float4*)(outcat + (size_t)i*512))[tid];
  __syncthreads();
  const int p = tid & 255, sel = tid >> 8;
  const float* W = sel ? W1bT : W1aT;
  float acc = sel ? 0.f : b1[p];
  #pragma unroll 8
  for (int cc = 0; cc < 512; ++cc) acc += orow[cc] * W[cc*256 + p];
  (sel ? bP : aP)[(size_t)i*256 + p] = acc;
}

// ------------------------------ fused MLP -----------------------------------
__global__ __launch_bounds__(256, 2) void mlp_kernel(
    const float* __restrict__ aP, const float* __restrict__ bP,
    const _Float16* __restrict__ W2h, const _Float16* __restrict__ W3h,
    const float* __restrict__ b2, const float* __restrict__ b3p,
    float* __restrict__ outp)
{
  __shared__ _Float16 lds[32768];   // 64KB union: W2 quarter (32KB) / h2 (64KB)
  const int tid = threadIdx.x;
  const int wv  = tid >> 6;
  const int ln  = tid & 31;
  const int hi  = (tid >> 5) & 1;
  const int i     = blockIdx.x >> 2;
  const int jbase = (blockIdx.x & 3) * 128;
  const int j     = jbase + wv*32 + ln;

  f32x16 acc[8];
  #pragma unroll
  for (int nt = 0; nt < 8; ++nt){
    #pragma unroll
    for (int e = 0; e < 16; ++e) acc[nt][e] = 0.f;
  }

  const float* arow = aP + (size_t)i*256;
  const float* brow = bP + (size_t)j*256;

  for (int p = 0; p < 4; ++p){
    if (p) __syncthreads();
    { // stage W2 quarter: rows n=tid, 64 k's, st_16x32 XOR swizzle
      const _Float16* src = W2h + tid*256 + p*64;
      char* dst = (char*)lds + tid*128;
      const int sw = (tid & 7) << 4;
      #pragma unroll
      for (int cc = 0; cc < 8; ++cc){
        f16x8 v = *(const f16x8*)(src + cc*8);
        *(f16x8*)(dst + ((cc*16) ^ sw)) = v;
      }
    }
    __syncthreads();
    #pragma unroll
    for (int ktl = 0; ktl < 4; ++ktl){
      const int kg = (p*4 + ktl)*16 + hi*8;
      float4 a0 = *(const float4*)(arow + kg);
      float4 a1 = *(const float4*)(arow + kg + 4);
      float4 b0 = *(const float4*)(brow + kg);
      float4 b1v = *(const float4*)(brow + kg + 4);
      f16x8 af;
      af[0] = (_Float16)fmaxf(a0.x + b0.x, 0.f);
      af[1] = (_Float16)fmaxf(a0.y + b0.y, 0.f);
      af[2] = (_Float16)fmaxf(a0.z + b0.z, 0.f);
      af[3] = (_Float16)fmaxf(a0.w + b0.w, 0.f);
      af[4] = (_Float16)fmaxf(a1.x + b1v.x, 0.f);
      af[5] = (_Float16)fmaxf(a1.y + b1v.y, 0.f);
      af[6] = (_Float16)fmaxf(a1.z + b1v.z, 0.f);
      af[7] = (_Float16)fmaxf(a1.w + b1v.w, 0.f);
      const int kl2 = (ktl*16 + hi*8) * 2;
      #pragma unroll
      for (int nt = 0; nt < 8; ++nt){
        const int n = nt*32 + ln;
        f16x8 bf = *(const f16x8*)((char*)lds + n*128 + (kl2 ^ ((n & 7) << 4)));
        acc[nt] = __builtin_amdgcn_mfma_f32_32x32x16_f16(af, bf, acc[nt], 0, 0, 0);
      }
    }
  }
  __syncthreads();
  // h2 -> LDS [128 pairs][256 ch] f16, XOR-swizzled per pair-row
  #pragma unroll
  for (int nt = 0; nt < 8; ++nt){
    const int ch = nt*32 + ln;
    const float bb = b2[ch];
    #pragma unroll
    for (int r = 0; r < 16; ++r){
      const int pr = wv*32 + (r & 3) + 8*(r >> 2) + 4*hi;
      const float v = fmaxf(acc[nt][r] + bb, 0.f);
      *(_Float16*)((char*)lds + pr*512 + ((ch*2) ^ ((pr & 7) << 4))) = (_Float16)v;
    }
  }
  __syncthreads();
  // logits
  f32x16 acc2[2];
  #pragma unroll
  for (int nt = 0; nt < 2; ++nt){
    #pragma unroll
    for (int e = 0; e < 16; ++e) acc2[nt][e] = 0.f;
  }
  const int pr = wv*32 + ln;
  const int sw2 = (pr & 7) << 4;
  #pragma unroll
  for (int kt = 0; kt < 16; ++kt){
    const int kb = kt*16 + hi*8;
    f16x8 a2 = *(const f16x8*)((char*)lds + pr*512 + ((kb*2) ^ sw2));
    #pragma unroll
    for (int nt = 0; nt < 2; ++nt){
      const int n = nt*32 + ln;
      f16x8 bf = *(const f16x8*)(W3h + n*256 + kb);
      acc2[nt] = __builtin_amdgcn_mfma_f32_32x32x16_f16(a2, bf, acc2[nt], 0, 0, 0);
    }
  }
  // log_softmax over 50 classes
  const float b30 = b3p[ln], b31 = b3p[32 + ln];
  const bool ok2 = (ln < 18);
  #pragma unroll
  for (int qr = 0; qr < 16; ++qr){
    const int r = (qr & 3) + 8*(qr >> 2) + 4*hi;
    float v0 = acc2[0][qr] + b30;
    float v1 = acc2[1][qr] + b31;
    float m = ok2 ? fmaxf(v0, v1) : v0;
    #pragma unroll
    for (int d = 1; d < 32; d <<= 1) m = fmaxf(m, __shfl_xor(m, d));
    float s = __expf(v0 - m) + (ok2 ? __expf(v1 - m) : 0.f);
    #pragma unroll
    for (int d = 1; d < 32; d <<= 1) s += __shfl_xor(s, d);
    const float lse = m + __logf(s);
    const size_t base = ((size_t)(i*512 + jbase + wv*32 + r)) * 50;
    outp[base + ln] = v0 - lse;
    if (ok2) outp[base + 32 + ln] = v1 - lse;
  }
}

// ------------------------------ launch --------------------------------------
extern "C" void kernel_launch(void* const* d_in, const int* in_sizes, int n_in,
                              void* d_out, int out_size, void* d_ws, size_t ws_size,
                              hipStream_t stream)
{
  const float* x     = (const float*)d_in[0];
  const float* Wih_f = (const float*)d_in[1];
  const float* Whh_f = (const float*)d_in[2];
  const float* bih_f = (const float*)d_in[3];
  const float* bhh_f = (const float*)d_in[4];
  const float* Wih_b = (const float*)d_in[5];
  const float* Whh_b = (const float*)d_in[6];
  const float* bih_b = (const float*)d_in[7];
  const float* bhh_b = (const float*)d_in[8];
  const float* W1    = (const float*)d_in[9];
  const float* b1    = (const float*)d_in[10];
  const float* W2    = (const float*)d_in[11];
  const float* b2    = (const float*)d_in[12];
  const float* W3    = (const float*)d_in[13];
  const float* b3    = (const float*)d_in[14];

  char* ws = (char*)d_ws;
  float*    xb     = (float*)(ws + 0);            // 4,194,304
  float*    outcat = (float*)(ws + 4194304);      // 1,048,576
  float*    aP     = (float*)(ws + 5242880);      //   524,288
  float*    bP     = (float*)(ws + 5767168);      //   524,288
  float*    WihT   = (float*)(ws + 6291456);      // 2,457,600 (dead after xb)
  _Float16* Wg     = (_Float16*)(ws + 6291456);   //   524,288 (aliases WihT)
  float*    W1aT   = (float*)(ws + 8749056);      //   524,288
  float*    W1bT   = (float*)(ws + 9273344);      //   524,288
  _Float16* W2h    = (_Float16*)(ws + 9797632);   //   131,072
  _Float16* W3h    = (_Float16*)(ws + 9928704);   //    32,768
  float*    b3p    = (float*)(ws + 9961472);      //       256

  if (ws_size < 9963808) return;   // leaves d_out poisoned -> clean failure

  prep_kernel<<<3745, 256, 0, stream>>>(Wih_f, Wih_b, W1, W2, W3, b3,
                                        WihT, W1aT, W1bT, W2h, W3h, b3p);
  xb_kernel<<<256, 256, 0, stream>>>(x, WihT, bih_f, bhh_f, bih_b, bhh_b, xb);
  prep2_kernel<<<64, 256, 0, stream>>>(Whh_f, Whh_b, Wg);   // after xb: Wg aliases WihT
  lstm_kernel<<<2, 512, 0, stream>>>(Whh_f, Whh_b, xb, outcat, Wg);
  ab_kernel<<<512, 512, 0, stream>>>(outcat, W1aT, W1bT, b1, aP, bP);
  mlp_kernel<<<2048, 256, 0, stream>>>(aP, bP, W2h, W3h, b2, b3p, (float*)d_out);
}

// Round 14
// 1060.568 us; speedup vs baseline: 2.3942x; 2.3942x over previous
//
#include <hip/hip_runtime.h>
#include <hip/hip_bf16.h>
#include <hip/hip_fp16.h>

// ---------------------------------------------------------------------------
// BiLSTM (N=512, D_IN=300, H=256) + pairwise 3-layer MLP (4H->H->H->50)
// + log_softmax, on MI355X.
//
//   lstm (round-14 = round-10 exact, best measured 862us): MFMA recurrence,
//   rows permuted row'=unit*4+gate; 6 tiles in register frags (AGPR-native
//   for MFMA), 2 tiles fragment-packed in LDS (conflict-free b128); B = h
//   broadcast; owner lanes write f32x4 gates to gl; 256-thread gate phase;
//   2 barriers/step. (r13 lesson: global streaming = 128KB/CU >> 32KB L1,
//   L2 latency unhidable under the serial step dependency -> LDS only.)
//   ab: 2 i's/block, float2 W loads (half the load instrs of r10's ab).
// ---------------------------------------------------------------------------

typedef _Float16 f16x2 __attribute__((ext_vector_type(2)));
typedef _Float16 f16x8 __attribute__((ext_vector_type(8)));
typedef float    f32x4  __attribute__((ext_vector_type(4)));
typedef float    f32x16 __attribute__((ext_vector_type(16)));

__device__ __forceinline__ float sigf(float x){ return 1.f/(1.f + __expf(-x)); }

// ------------------------------ prep ---------------------------------------
__global__ __launch_bounds__(256) void prep_kernel(
    const float* __restrict__ Wih_f, const float* __restrict__ Wih_b,
    const float* __restrict__ W1,    const float* __restrict__ W2,
    const float* __restrict__ W3,    const float* __restrict__ b3,
    float* __restrict__ WihT, float* __restrict__ W1aT, float* __restrict__ W1bT,
    _Float16* __restrict__ W2h, _Float16* __restrict__ W3h,
    float* __restrict__ b3p)
{
  int idx = blockIdx.x * 256 + threadIdx.x;
  if (idx < 614400){                     // WihT[d][c][r] = Wih_d[r][c]
    int d = idx / 307200, r2 = idx % 307200;
    int cc = r2 / 1024, rr = r2 % 1024;
    const float* src = d ? Wih_b : Wih_f;
    WihT[idx] = src[rr*300 + cc];
    return;
  }
  idx -= 614400;
  if (idx < 262144){                     // W1aT[c][p]=W1[p][c]; W1bT[c][p]=W1[p][512+c]
    int sel = idx / 131072, r2 = idx % 131072;
    int cc = r2 / 256, pp = r2 % 256;
    float v = W1[pp*1024 + sel*512 + cc];
    (sel ? W1bT : W1aT)[r2] = v;
    return;
  }
  idx -= 262144;
  if (idx < 65536){ W2h[idx] = (_Float16)W2[idx]; return; }
  idx -= 65536;
  if (idx < 16384){                      // W3h padded to [64][256]
    int n = idx >> 8, k = idx & 255;
    W3h[idx] = (n < 50) ? (_Float16)W3[n*256 + k] : (_Float16)0.f;
    return;
  }
  idx -= 16384;
  if (idx < 64){ b3p[idx] = (idx < 50) ? b3[idx] : 0.f; return; }
}

// ------------------------------ xb ------------------------------------------
// Writes PERMUTED layout: xb'[t][unit*4 + gate]  (float4 per unit, coalesced)
__global__ __launch_bounds__(256) void xb_kernel(
    const float* __restrict__ x, const float* __restrict__ WihT,
    const float* __restrict__ bih_f, const float* __restrict__ bhh_f,
    const float* __restrict__ bih_b, const float* __restrict__ bhh_b,
    float* __restrict__ xb)
{
  const int tid = threadIdx.x;
  const int dir = blockIdx.x >> 7;
  const int t0  = (blockIdx.x & 127) * 4;
  __shared__ float xs[4][304];
  #pragma unroll
  for (int tt = 0; tt < 4; ++tt)
    if (tid < 75) ((float4*)xs[tt])[tid] = ((const float4*)(x + (size_t)(t0+tt)*300))[tid];
  __syncthreads();
  const float* W = WihT + dir*307200;
  float acc[4][4];
  #pragma unroll
  for (int r = 0; r < 4; ++r){
    #pragma unroll
    for (int tt = 0; tt < 4; ++tt) acc[r][tt] = 0.f;
  }
  for (int c = 0; c < 300; ++c){
    float x0 = xs[0][c], x1 = xs[1][c], x2 = xs[2][c], x3 = xs[3][c];
    #pragma unroll
    for (int r = 0; r < 4; ++r){
      float wv = W[c*1024 + r*256 + tid];
      acc[r][0] += wv*x0; acc[r][1] += wv*x1; acc[r][2] += wv*x2; acc[r][3] += wv*x3;
    }
  }
  const float* bih = dir ? bih_b : bih_f;
  const float* bhh = dir ? bhh_b : bhh_f;
  float bias[4];
  #pragma unroll
  for (int r = 0; r < 4; ++r) bias[r] = bih[r*256 + tid] + bhh[r*256 + tid];
  float* xbd = xb + (size_t)dir*512*1024;
  #pragma unroll
  for (int tt = 0; tt < 4; ++tt){
    float4 v;
    v.x = acc[0][tt] + bias[0];
    v.y = acc[1][tt] + bias[1];
    v.z = acc[2][tt] + bias[2];
    v.w = acc[3][tt] + bias[3];
    *(float4*)(xbd + (size_t)(t0+tt)*1024 + tid*4) = v;
  }
}

// ------------------------------ lstm ----------------------------------------
#define MFMA16(A, B, C) __builtin_amdgcn_mfma_f32_16x16x32_f16((A), (B), (C), 0, 0, 0)

__global__ __launch_bounds__(512)
__attribute__((amdgpu_waves_per_eu(2, 2)))
void lstm_kernel(
    const float* __restrict__ Whh_f, const float* __restrict__ Whh_b,
    const float* __restrict__ xb, float* __restrict__ outcat)
{
  extern __shared__ char smem[];
  // [0,131072): A-frag LDS tiles (2 per wave, fragment-packed)
  // [131072,135168): gl  f32[1024]   (gate results, unit-major)
  // [135168,136192): hbuf f16[2][256]
  char*     wbase = smem;
  float*    gl    = (float*)(smem + 131072);
  _Float16* hbuf  = (_Float16*)(smem + 135168);

  const int tid = threadIdx.x;
  const int dir = blockIdx.x;
  const int w   = tid >> 6;
  const int l   = tid & 63;
  const int lg  = l >> 4;      // k-group (0..3)
  const int lr  = l & 15;      // row within tile
  const float* Whh = dir ? Whh_b : Whh_f;

  char* wl = wbase + w*16384 + l*16;      // this lane's A-frag slot base

  // ---- init: load + permute + cvt weights into frags
  // tile tt of wave w covers rows' [(w*8+tt)*16, +16) ; row'=unit*4+gate
  f16x8 wreg[48];                          // tiles 0..5 (192 regs, AGPR ok)
  #pragma unroll
  for (int tt = 0; tt < 8; ++tt){
    const int rowp = (w*8 + tt)*16 + lr;
    const int orow = (rowp & 3)*256 + (rowp >> 2);
    const float* src = Whh + (size_t)orow*256 + lg*8;
    #pragma unroll
    for (int c = 0; c < 8; ++c){
      float4 v0 = *(const float4*)(src + c*32);
      float4 v1 = *(const float4*)(src + c*32 + 4);
      f16x8 o;
      o[0]=(_Float16)v0.x; o[1]=(_Float16)v0.y; o[2]=(_Float16)v0.z; o[3]=(_Float16)v0.w;
      o[4]=(_Float16)v1.x; o[5]=(_Float16)v1.y; o[6]=(_Float16)v1.z; o[7]=(_Float16)v1.w;
      if (tt < 6) wreg[tt*8 + c] = o;
      else        *(f16x8*)(wl + ((tt - 6)*8 + c)*1024) = o;
    }
  }
  if (tid < 32) ((f16x8*)hbuf)[tid] = (f16x8)(_Float16)0.f;    // h_{-1} = 0
  __syncthreads();

  const float* xbd = xb + (size_t)dir*512*1024;
  float cst = 0.f;                         // c-state (threads < 256)

  for (int it = 0; it < 512; ++it){
    const int t = dir ? (511 - it) : it;
    float4 xb4;
    if (tid < 256) xb4 = *(const float4*)(xbd + (size_t)t*1024 + tid*4);

    // B fragments: h broadcast to all cols; lane slot j <- h[c*32 + lg*8 + j]
    const _Float16* hsrc = hbuf + (it & 1)*256 + lg*8;
    f16x8 hf[8];
    #pragma unroll
    for (int c = 0; c < 8; ++c) hf[c] = *(const f16x8*)(hsrc + c*32);

    const bool owner = (lr == 0);
    // tile pairs: (0,1) (2,3) reg-only; (4,6) (5,7) mix reg+LDS
    {
      f32x4 a0 = {0.f,0.f,0.f,0.f}, a1 = {0.f,0.f,0.f,0.f};
      #pragma unroll
      for (int c = 0; c < 8; ++c){
        a0 = MFMA16(wreg[0*8+c], hf[c], a0);
        a1 = MFMA16(wreg[1*8+c], hf[c], a1);
      }
      if (owner){
        *(f32x4*)(gl + ((w*8+0)*4 + lg)*4) = a0;
        *(f32x4*)(gl + ((w*8+1)*4 + lg)*4) = a1;
      }
    }
    {
      f32x4 a0 = {0.f,0.f,0.f,0.f}, a1 = {0.f,0.f,0.f,0.f};
      #pragma unroll
      for (int c = 0; c < 8; ++c){
        a0 = MFMA16(wreg[2*8+c], hf[c], a0);
        a1 = MFMA16(wreg[3*8+c], hf[c], a1);
      }
      if (owner){
        *(f32x4*)(gl + ((w*8+2)*4 + lg)*4) = a0;
        *(f32x4*)(gl + ((w*8+3)*4 + lg)*4) = a1;
      }
    }
    {
      f32x4 a0 = {0.f,0.f,0.f,0.f}, a1 = {0.f,0.f,0.f,0.f};
      #pragma unroll
      for (int c = 0; c < 8; ++c){
        f16x8 w6 = *(const f16x8*)(wl + (0*8 + c)*1024);
        a0 = MFMA16(wreg[4*8+c], hf[c], a0);
        a1 = MFMA16(w6, hf[c], a1);
      }
      if (owner){
        *(f32x4*)(gl + ((w*8+4)*4 + lg)*4) = a0;
        *(f32x4*)(gl + ((w*8+6)*4 + lg)*4) = a1;
      }
    }
    {
      f32x4 a0 = {0.f,0.f,0.f,0.f}, a1 = {0.f,0.f,0.f,0.f};
      #pragma unroll
      for (int c = 0; c < 8; ++c){
        f16x8 w7 = *(const f16x8*)(wl + (1*8 + c)*1024);
        a0 = MFMA16(wreg[5*8+c], hf[c], a0);
        a1 = MFMA16(w7, hf[c], a1);
      }
      if (owner){
        *(f32x4*)(gl + ((w*8+5)*4 + lg)*4) = a0;
        *(f32x4*)(gl + ((w*8+7)*4 + lg)*4) = a1;
      }
    }
    __syncthreads();                       // gl complete

    if (tid < 256){
      f32x4 g4 = *(const f32x4*)(gl + tid*4);
      const float gi = g4[0] + xb4.x;
      const float gf = g4[1] + xb4.y;
      const float gg = g4[2] + xb4.z;
      const float go = g4[3] + xb4.w;
      const float iv = sigf(gi);
      const float fv = sigf(gf);
      const float gv = fmaf(sigf(2.f*gg), 2.f, -1.f);    // tanh
      const float ov = sigf(go);
      cst = fmaf(fv, cst, iv*gv);
      const float h = ov * fmaf(sigf(2.f*cst), 2.f, -1.f);
      hbuf[((it + 1) & 1)*256 + tid] = (_Float16)h;
      outcat[(size_t)t*512 + dir*256 + tid] = h;
    }
    __syncthreads();                       // hbuf ready for next step
  }
}

// ------------------------------ ab ------------------------------------------
// grid 256: block handles 2 sequence positions; thread = (io, sel, q) owns
// outputs p = 2q, 2q+1 of (sel ? bP : aP)[i0+io]. float2 W loads (coalesced).
__global__ __launch_bounds__(512) void ab_kernel(
    const float* __restrict__ outcat, const float* __restrict__ W1aT,
    const float* __restrict__ W1bT,  const float* __restrict__ b1,
    float* __restrict__ aP, float* __restrict__ bP)
{
  __shared__ float orow[2][512];
  const int tid = threadIdx.x;
  const int i0 = blockIdx.x * 2;
  if (tid < 256)
    ((float4*)orow[tid >> 7])[tid & 127] =
        ((const float4*)(outcat + (size_t)(i0 + (tid >> 7))*512))[tid & 127];
  __syncthreads();
  const int io  = tid >> 8;
  const int g   = tid & 255;
  const int sel = g >> 7;
  const int q   = g & 127;
  const int p0  = q * 2;
  const float* W = sel ? W1bT : W1aT;
  const float* xr = orow[io];
  float acc0 = sel ? 0.f : b1[p0];
  float acc1 = sel ? 0.f : b1[p0 + 1];
  #pragma unroll 8
  for (int cc = 0; cc < 512; ++cc){
    const float2 wv = *(const float2*)(W + cc*256 + p0);
    const float xc = xr[cc];
    acc0 = fmaf(wv.x, xc, acc0);
    acc1 = fmaf(wv.y, xc, acc1);
  }
  float2 r; r.x = acc0; r.y = acc1;
  *(float2*)((sel ? bP : aP) + (size_t)(i0 + io)*256 + p0) = r;
}

// ------------------------------ fused MLP -----------------------------------
__global__ __launch_bounds__(256, 2) void mlp_kernel(
    const float* __restrict__ aP, const float* __restrict__ bP,
    const _Float16* __restrict__ W2h, const _Float16* __restrict__ W3h,
    const float* __restrict__ b2, const float* __restrict__ b3p,
    float* __restrict__ outp)
{
  __shared__ _Float16 lds[32768];   // 64KB union: W2 quarter (32KB) / h2 (64KB)
  const int tid = threadIdx.x;
  const int wv  = tid >> 6;
  const int ln  = tid & 31;
  const int hi  = (tid >> 5) & 1;
  const int i     = blockIdx.x >> 2;
  const int jbase = (blockIdx.x & 3) * 128;
  const int j     = jbase + wv*32 + ln;

  f32x16 acc[8];
  #pragma unroll
  for (int nt = 0; nt < 8; ++nt){
    #pragma unroll
    for (int e = 0; e < 16; ++e) acc[nt][e] = 0.f;
  }

  const float* arow = aP + (size_t)i*256;
  const float* brow = bP + (size_t)j*256;

  for (int p = 0; p < 4; ++p){
    if (p) __syncthreads();
    { // stage W2 quarter: rows n=tid, 64 k's, st_16x32 XOR swizzle
      const _Float16* src = W2h + tid*256 + p*64;
      char* dst = (char*)lds + tid*128;
      const int sw = (tid & 7) << 4;
      #pragma unroll
      for (int cc = 0; cc < 8; ++cc){
        f16x8 v = *(const f16x8*)(src + cc*8);
        *(f16x8*)(dst + ((cc*16) ^ sw)) = v;
      }
    }
    __syncthreads();
    #pragma unroll
    for (int ktl = 0; ktl < 4; ++ktl){
      const int kg = (p*4 + ktl)*16 + hi*8;
      float4 a0 = *(const float4*)(arow + kg);
      float4 a1 = *(const float4*)(arow + kg + 4);
      float4 b0 = *(const float4*)(brow + kg);
      float4 b1v = *(const float4*)(brow + kg + 4);
      f16x8 af;
      af[0] = (_Float16)fmaxf(a0.x + b0.x, 0.f);
      af[1] = (_Float16)fmaxf(a0.y + b0.y, 0.f);
      af[2] = (_Float16)fmaxf(a0.z + b0.z, 0.f);
      af[3] = (_Float16)fmaxf(a0.w + b0.w, 0.f);
      af[4] = (_Float16)fmaxf(a1.x + b1v.x, 0.f);
      af[5] = (_Float16)fmaxf(a1.y + b1v.y, 0.f);
      af[6] = (_Float16)fmaxf(a1.z + b1v.z, 0.f);
      af[7] = (_Float16)fmaxf(a1.w + b1v.w, 0.f);
      const int kl2 = (ktl*16 + hi*8) * 2;
      #pragma unroll
      for (int nt = 0; nt < 8; ++nt){
        const int n = nt*32 + ln;
        f16x8 bf = *(const f16x8*)((char*)lds + n*128 + (kl2 ^ ((n & 7) << 4)));
        acc[nt] = __builtin_amdgcn_mfma_f32_32x32x16_f16(af, bf, acc[nt], 0, 0, 0);
      }
    }
  }
  __syncthreads();
  // h2 -> LDS [128 pairs][256 ch] f16, XOR-swizzled per pair-row
  #pragma unroll
  for (int nt = 0; nt < 8; ++nt){
    const int ch = nt*32 + ln;
    const float bb = b2[ch];
    #pragma unroll
    for (int r = 0; r < 16; ++r){
      const int pr = wv*32 + (r & 3) + 8*(r >> 2) + 4*hi;
      const float v = fmaxf(acc[nt][r] + bb, 0.f);
      *(_Float16*)((char*)lds + pr*512 + ((ch*2) ^ ((pr & 7) << 4))) = (_Float16)v;
    }
  }
  __syncthreads();
  // logits
  f32x16 acc2[2];
  #pragma unroll
  for (int nt = 0; nt < 2; ++nt){
    #pragma unroll
    for (int e = 0; e < 16; ++e) acc2[nt][e] = 0.f;
  }
  const int pr = wv*32 + ln;
  const int sw2 = (pr & 7) << 4;
  #pragma unroll
  for (int kt = 0; kt < 16; ++kt){
    const int kb = kt*16 + hi*8;
    f16x8 a2 = *(const f16x8*)((char*)lds + pr*512 + ((kb*2) ^ sw2));
    #pragma unroll
    for (int nt = 0; nt < 2; ++nt){
      const int n = nt*32 + ln;
      f16x8 bf = *(const f16x8*)(W3h + n*256 + kb);
      acc2[nt] = __builtin_amdgcn_mfma_f32_32x32x16_f16(a2, bf, acc2[nt], 0, 0, 0);
    }
  }
  // log_softmax over 50 classes
  const float b30 = b3p[ln], b31 = b3p[32 + ln];
  const bool ok2 = (ln < 18);
  #pragma unroll
  for (int qr = 0; qr < 16; ++qr){
    const int r = (qr & 3) + 8*(qr >> 2) + 4*hi;
    float v0 = acc2[0][qr] + b30;
    float v1 = acc2[1][qr] + b31;
    float m = ok2 ? fmaxf(v0, v1) : v0;
    #pragma unroll
    for (int d = 1; d < 32; d <<= 1) m = fmaxf(m, __shfl_xor(m, d));
    float s = __expf(v0 - m) + (ok2 ? __expf(v1 - m) : 0.f);
    #pragma unroll
    for (int d = 1; d < 32; d <<= 1) s += __shfl_xor(s, d);
    const float lse = m + __logf(s);
    const size_t base = ((size_t)(i*512 + jbase + wv*32 + r)) * 50;
    outp[base + ln] = v0 - lse;
    if (ok2) outp[base + 32 + ln] = v1 - lse;
  }
}

// ------------------------------ launch --------------------------------------
extern "C" void kernel_launch(void* const* d_in, const int* in_sizes, int n_in,
                              void* d_out, int out_size, void* d_ws, size_t ws_size,
                              hipStream_t stream)
{
  const float* x     = (const float*)d_in[0];
  const float* Wih_f = (const float*)d_in[1];
  const float* Whh_f = (const float*)d_in[2];
  const float* bih_f = (const float*)d_in[3];
  const float* bhh_f = (const float*)d_in[4];
  const float* Wih_b = (const float*)d_in[5];
  const float* Whh_b = (const float*)d_in[6];
  const float* bih_b = (const float*)d_in[7];
  const float* bhh_b = (const float*)d_in[8];
  const float* W1    = (const float*)d_in[9];
  const float* b1    = (const float*)d_in[10];
  const float* W2    = (const float*)d_in[11];
  const float* b2    = (const float*)d_in[12];
  const float* W3    = (const float*)d_in[13];
  const float* b3    = (const float*)d_in[14];

  char* ws = (char*)d_ws;
  float*    xb     = (float*)(ws + 0);            // 4,194,304
  float*    outcat = (float*)(ws + 4194304);      // 1,048,576
  float*    aP     = (float*)(ws + 5242880);      //   524,288
  float*    bP     = (float*)(ws + 5767168);      //   524,288
  float*    WihT   = (float*)(ws + 6291456);      // 2,457,600
  float*    W1aT   = (float*)(ws + 8749056);      //   524,288
  float*    W1bT   = (float*)(ws + 9273344);      //   524,288
  _Float16* W2h    = (_Float16*)(ws + 9797632);   //   131,072
  _Float16* W3h    = (_Float16*)(ws + 9928704);   //    32,768
  float*    b3p    = (float*)(ws + 9961472);      //       256

  if (ws_size < 9963808) return;   // leaves d_out poisoned -> clean failure

  // lstm needs 136,192 B of dynamic LDS (>64 KB static limit)
  (void)hipFuncSetAttribute((const void*)lstm_kernel,
                            hipFuncAttributeMaxDynamicSharedMemorySize, 136192);

  prep_kernel<<<3745, 256, 0, stream>>>(Wih_f, Wih_b, W1, W2, W3, b3,
                                        WihT, W1aT, W1bT, W2h, W3h, b3p);
  xb_kernel<<<256, 256, 0, stream>>>(x, WihT, bih_f, bhh_f, bih_b, bhh_b, xb);
  lstm_kernel<<<2, 512, 136192, stream>>>(Whh_f, Whh_b, xb, outcat);
  ab_kernel<<<256, 512, 0, stream>>>(outcat, W1aT, W1bT, b1, aP, bP);
  mlp_kernel<<<2048, 256, 0, stream>>>(aP, bP, W2h, W3h, b2, b3p, (float*)d_out);
}

// Round 15
// 1055.903 us; speedup vs baseline: 2.4048x; 1.0044x over previous
//
#include <hip/hip_runtime.h>
#include <hip/hip_bf16.h>
#include <hip/hip_fp16.h>

// ---------------------------------------------------------------------------
// BiLSTM (N=512, D_IN=300, H=256) + pairwise 3-layer MLP (4H->H->H->50)
// + log_softmax, on MI355X.
//
//   lstm (round-15): r10's MFMA recurrence with a WAVE-LOCAL gate phase.
//   Wave w's owner lanes write its 8 tiles' gates to gl[w*32..w*32+31]
//   (same-wave region); lanes l<32 of wave w read those back (same-wave
//   LDS, ordered by lgkmcnt -- NO barrier), gate-compute 32 units each
//   wave in parallel, write h to hbuf/outcat. ONE barrier/step (was 2);
//   double-buffered hbuf makes it race-free. MFMA structure = r10 exact.
// ---------------------------------------------------------------------------

typedef _Float16 f16x2 __attribute__((ext_vector_type(2)));
typedef _Float16 f16x8 __attribute__((ext_vector_type(8)));
typedef float    f32x4  __attribute__((ext_vector_type(4)));
typedef float    f32x16 __attribute__((ext_vector_type(16)));

__device__ __forceinline__ float sigf(float x){ return 1.f/(1.f + __expf(-x)); }

// ------------------------------ prep ---------------------------------------
__global__ __launch_bounds__(256) void prep_kernel(
    const float* __restrict__ Wih_f, const float* __restrict__ Wih_b,
    const float* __restrict__ W1,    const float* __restrict__ W2,
    const float* __restrict__ W3,    const float* __restrict__ b3,
    float* __restrict__ WihT, float* __restrict__ W1aT, float* __restrict__ W1bT,
    _Float16* __restrict__ W2h, _Float16* __restrict__ W3h,
    float* __restrict__ b3p)
{
  int idx = blockIdx.x * 256 + threadIdx.x;
  if (idx < 614400){                     // WihT[d][c][r] = Wih_d[r][c]
    int d = idx / 307200, r2 = idx % 307200;
    int cc = r2 / 1024, rr = r2 % 1024;
    const float* src = d ? Wih_b : Wih_f;
    WihT[idx] = src[rr*300 + cc];
    return;
  }
  idx -= 614400;
  if (idx < 262144){                     // W1aT[c][p]=W1[p][c]; W1bT[c][p]=W1[p][512+c]
    int sel = idx / 131072, r2 = idx % 131072;
    int cc = r2 / 256, pp = r2 % 256;
    float v = W1[pp*1024 + sel*512 + cc];
    (sel ? W1bT : W1aT)[r2] = v;
    return;
  }
  idx -= 262144;
  if (idx < 65536){ W2h[idx] = (_Float16)W2[idx]; return; }
  idx -= 65536;
  if (idx < 16384){                      // W3h padded to [64][256]
    int n = idx >> 8, k = idx & 255;
    W3h[idx] = (n < 50) ? (_Float16)W3[n*256 + k] : (_Float16)0.f;
    return;
  }
  idx -= 16384;
  if (idx < 64){ b3p[idx] = (idx < 50) ? b3[idx] : 0.f; return; }
}

// ------------------------------ xb ------------------------------------------
// Writes PERMUTED layout: xb'[t][unit*4 + gate]  (float4 per unit, coalesced)
__global__ __launch_bounds__(256) void xb_kernel(
    const float* __restrict__ x, const float* __restrict__ WihT,
    const float* __restrict__ bih_f, const float* __restrict__ bhh_f,
    const float* __restrict__ bih_b, const float* __restrict__ bhh_b,
    float* __restrict__ xb)
{
  const int tid = threadIdx.x;
  const int dir = blockIdx.x >> 7;
  const int t0  = (blockIdx.x & 127) * 4;
  __shared__ float xs[4][304];
  #pragma unroll
  for (int tt = 0; tt < 4; ++tt)
    if (tid < 75) ((float4*)xs[tt])[tid] = ((const float4*)(x + (size_t)(t0+tt)*300))[tid];
  __syncthreads();
  const float* W = WihT + dir*307200;
  float acc[4][4];
  #pragma unroll
  for (int r = 0; r < 4; ++r){
    #pragma unroll
    for (int tt = 0; tt < 4; ++tt) acc[r][tt] = 0.f;
  }
  for (int c = 0; c < 300; ++c){
    float x0 = xs[0][c], x1 = xs[1][c], x2 = xs[2][c], x3 = xs[3][c];
    #pragma unroll
    for (int r = 0; r < 4; ++r){
      float wv = W[c*1024 + r*256 + tid];
      acc[r][0] += wv*x0; acc[r][1] += wv*x1; acc[r][2] += wv*x2; acc[r][3] += wv*x3;
    }
  }
  const float* bih = dir ? bih_b : bih_f;
  const float* bhh = dir ? bhh_b : bhh_f;
  float bias[4];
  #pragma unroll
  for (int r = 0; r < 4; ++r) bias[r] = bih[r*256 + tid] + bhh[r*256 + tid];
  float* xbd = xb + (size_t)dir*512*1024;
  #pragma unroll
  for (int tt = 0; tt < 4; ++tt){
    float4 v;
    v.x = acc[0][tt] + bias[0];
    v.y = acc[1][tt] + bias[1];
    v.z = acc[2][tt] + bias[2];
    v.w = acc[3][tt] + bias[3];
    *(float4*)(xbd + (size_t)(t0+tt)*1024 + tid*4) = v;
  }
}

// ------------------------------ lstm ----------------------------------------
#define MFMA16(A, B, C) __builtin_amdgcn_mfma_f32_16x16x32_f16((A), (B), (C), 0, 0, 0)

__global__ __launch_bounds__(512)
__attribute__((amdgpu_waves_per_eu(2, 2)))
void lstm_kernel(
    const float* __restrict__ Whh_f, const float* __restrict__ Whh_b,
    const float* __restrict__ xb, float* __restrict__ outcat)
{
  extern __shared__ char smem[];
  // [0,131072): A-frag LDS tiles (2 per wave, fragment-packed)
  // [131072,135168): gl  f32[1024]   (per-wave slices, unit-major)
  // [135168,136192): hbuf f16[2][256]
  char*     wbase = smem;
  float*    gl    = (float*)(smem + 131072);
  _Float16* hbuf  = (_Float16*)(smem + 135168);

  const int tid = threadIdx.x;
  const int dir = blockIdx.x;
  const int w   = tid >> 6;
  const int l   = tid & 63;
  const int lg  = l >> 4;      // k-group (0..3)
  const int lr  = l & 15;      // row within tile
  const float* Whh = dir ? Whh_b : Whh_f;

  char* wl = wbase + w*16384 + l*16;      // this lane's A-frag slot base

  // ---- init: load + permute + cvt weights into frags
  // tile tt of wave w covers rows' [(w*8+tt)*16, +16) ; row'=unit*4+gate
  f16x8 wreg[48];                          // tiles 0..5 (192 regs, AGPR ok)
  #pragma unroll
  for (int tt = 0; tt < 8; ++tt){
    const int rowp = (w*8 + tt)*16 + lr;
    const int orow = (rowp & 3)*256 + (rowp >> 2);
    const float* src = Whh + (size_t)orow*256 + lg*8;
    #pragma unroll
    for (int c = 0; c < 8; ++c){
      float4 v0 = *(const float4*)(src + c*32);
      float4 v1 = *(const float4*)(src + c*32 + 4);
      f16x8 o;
      o[0]=(_Float16)v0.x; o[1]=(_Float16)v0.y; o[2]=(_Float16)v0.z; o[3]=(_Float16)v0.w;
      o[4]=(_Float16)v1.x; o[5]=(_Float16)v1.y; o[6]=(_Float16)v1.z; o[7]=(_Float16)v1.w;
      if (tt < 6) wreg[tt*8 + c] = o;
      else        *(f16x8*)(wl + ((tt - 6)*8 + c)*1024) = o;
    }
  }
  if (tid < 32) ((f16x8*)hbuf)[tid] = (f16x8)(_Float16)0.f;    // h_{-1} = 0
  __syncthreads();

  const float* xbd = xb + (size_t)dir*512*1024;
  const int u = w*32 + l;                  // this lane's unit (valid iff l<32)
  float cst = 0.f;                         // c-state (lanes l<32 of each wave)

  for (int it = 0; it < 512; ++it){
    const int t = dir ? (511 - it) : it;
    float4 xb4;
    if (l < 32) xb4 = *(const float4*)(xbd + (size_t)t*1024 + u*4);

    // B fragments: h broadcast to all cols; lane slot j <- h[c*32 + lg*8 + j]
    const _Float16* hsrc = hbuf + (it & 1)*256 + lg*8;
    f16x8 hf[8];
    #pragma unroll
    for (int c = 0; c < 8; ++c) hf[c] = *(const f16x8*)(hsrc + c*32);

    const bool owner = (lr == 0);
    // tile pairs: (0,1) (2,3) reg-only; (4,6) (5,7) mix reg+LDS
    {
      f32x4 a0 = {0.f,0.f,0.f,0.f}, a1 = {0.f,0.f,0.f,0.f};
      #pragma unroll
      for (int c = 0; c < 8; ++c){
        a0 = MFMA16(wreg[0*8+c], hf[c], a0);
        a1 = MFMA16(wreg[1*8+c], hf[c], a1);
      }
      if (owner){
        *(f32x4*)(gl + ((w*8+0)*4 + lg)*4) = a0;
        *(f32x4*)(gl + ((w*8+1)*4 + lg)*4) = a1;
      }
    }
    {
      f32x4 a0 = {0.f,0.f,0.f,0.f}, a1 = {0.f,0.f,0.f,0.f};
      #pragma unroll
      for (int c = 0; c < 8; ++c){
        a0 = MFMA16(wreg[2*8+c], hf[c], a0);
        a1 = MFMA16(wreg[3*8+c], hf[c], a1);
      }
      if (owner){
        *(f32x4*)(gl + ((w*8+2)*4 + lg)*4) = a0;
        *(f32x4*)(gl + ((w*8+3)*4 + lg)*4) = a1;
      }
    }
    {
      f32x4 a0 = {0.f,0.f,0.f,0.f}, a1 = {0.f,0.f,0.f,0.f};
      #pragma unroll
      for (int c = 0; c < 8; ++c){
        f16x8 w6 = *(const f16x8*)(wl + (0*8 + c)*1024);
        a0 = MFMA16(wreg[4*8+c], hf[c], a0);
        a1 = MFMA16(w6, hf[c], a1);
      }
      if (owner){
        *(f32x4*)(gl + ((w*8+4)*4 + lg)*4) = a0;
        *(f32x4*)(gl + ((w*8+6)*4 + lg)*4) = a1;
      }
    }
    {
      f32x4 a0 = {0.f,0.f,0.f,0.f}, a1 = {0.f,0.f,0.f,0.f};
      #pragma unroll
      for (int c = 0; c < 8; ++c){
        f16x8 w7 = *(const f16x8*)(wl + (1*8 + c)*1024);
        a0 = MFMA16(wreg[5*8+c], hf[c], a0);
        a1 = MFMA16(w7, hf[c], a1);
      }
      if (owner){
        *(f32x4*)(gl + ((w*8+5)*4 + lg)*4) = a0;
        *(f32x4*)(gl + ((w*8+7)*4 + lg)*4) = a1;
      }
    }
    // wave-local gate: lanes l<32 read back THIS wave's gl slice
    // (same-wave LDS write->read, ordered by lgkmcnt -- no barrier)
    if (l < 32){
      f32x4 g4 = *(const f32x4*)(gl + u*4);
      const float gi = g4[0] + xb4.x;
      const float gf = g4[1] + xb4.y;
      const float gg = g4[2] + xb4.z;
      const float go = g4[3] + xb4.w;
      const float iv = sigf(gi);
      const float fv = sigf(gf);
      const float gv = fmaf(sigf(2.f*gg), 2.f, -1.f);    // tanh
      const float ov = sigf(go);
      cst = fmaf(fv, cst, iv*gv);
      const float h = ov * fmaf(sigf(2.f*cst), 2.f, -1.f);
      hbuf[((it + 1) & 1)*256 + u] = (_Float16)h;
      outcat[(size_t)t*512 + dir*256 + u] = h;
    }
    __syncthreads();    // hbuf[(it+1)&1] complete; hbuf[it&1] reads done
  }
}

// ------------------------------ ab ------------------------------------------
// grid 256: block handles 2 sequence positions; thread = (io, sel, q) owns
// outputs p = 2q, 2q+1 of (sel ? bP : aP)[i0+io]. float2 W loads (coalesced).
__global__ __launch_bounds__(512) void ab_kernel(
    const float* __restrict__ outcat, const float* __restrict__ W1aT,
    const float* __restrict__ W1bT,  const float* __restrict__ b1,
    float* __restrict__ aP, float* __restrict__ bP)
{
  __shared__ float orow[2][512];
  const int tid = threadIdx.x;
  const int i0 = blockIdx.x * 2;
  if (tid < 256)
    ((float4*)orow[tid >> 7])[tid & 127] =
        ((const float4*)(outcat + (size_t)(i0 + (tid >> 7))*512))[tid & 127];
  __syncthreads();
  const int io  = tid >> 8;
  const int g   = tid & 255;
  const int sel = g >> 7;
  const int q   = g & 127;
  const int p0  = q * 2;
  const float* W = sel ? W1bT : W1aT;
  const float* xr = orow[io];
  float acc0 = sel ? 0.f : b1[p0];
  float acc1 = sel ? 0.f : b1[p0 + 1];
  #pragma unroll 8
  for (int cc = 0; cc < 512; ++cc){
    const float2 wv = *(const float2*)(W + cc*256 + p0);
    const float xc = xr[cc];
    acc0 = fmaf(wv.x, xc, acc0);
    acc1 = fmaf(wv.y, xc, acc1);
  }
  float2 r; r.x = acc0; r.y = acc1;
  *(float2*)((sel ? bP : aP) + (size_t)(i0 + io)*256 + p0) = r;
}

// ------------------------------ fused MLP -----------------------------------
__global__ __launch_bounds__(256, 2) void mlp_kernel(
    const float* __restrict__ aP, const float* __restrict__ bP,
    const _Float16* __restrict__ W2h, const _Float16* __restrict__ W3h,
    const float* __restrict__ b2, const float* __restrict__ b3p,
    float* __restrict__ outp)
{
  __shared__ _Float16 lds[32768];   // 64KB union: W2 quarter (32KB) / h2 (64KB)
  const int tid = threadIdx.x;
  const int wv  = tid >> 6;
  const int ln  = tid & 31;
  const int hi  = (tid >> 5) & 1;
  const int i     = blockIdx.x >> 2;
  const int jbase = (blockIdx.x & 3) * 128;
  const int j     = jbase + wv*32 + ln;

  f32x16 acc[8];
  #pragma unroll
  for (int nt = 0; nt < 8; ++nt){
    #pragma unroll
    for (int e = 0; e < 16; ++e) acc[nt][e] = 0.f;
  }

  const float* arow = aP + (size_t)i*256;
  const float* brow = bP + (size_t)j*256;

  for (int p = 0; p < 4; ++p){
    if (p) __syncthreads();
    { // stage W2 quarter: rows n=tid, 64 k's, st_16x32 XOR swizzle
      const _Float16* src = W2h + tid*256 + p*64;
      char* dst = (char*)lds + tid*128;
      const int sw = (tid & 7) << 4;
      #pragma unroll
      for (int cc = 0; cc < 8; ++cc){
        f16x8 v = *(const f16x8*)(src + cc*8);
        *(f16x8*)(dst + ((cc*16) ^ sw)) = v;
      }
    }
    __syncthreads();
    #pragma unroll
    for (int ktl = 0; ktl < 4; ++ktl){
      const int kg = (p*4 + ktl)*16 + hi*8;
      float4 a0 = *(const float4*)(arow + kg);
      float4 a1 = *(const float4*)(arow + kg + 4);
      float4 b0 = *(const float4*)(brow + kg);
      float4 b1v = *(const float4*)(brow + kg + 4);
      f16x8 af;
      af[0] = (_Float16)fmaxf(a0.x + b0.x, 0.f);
      af[1] = (_Float16)fmaxf(a0.y + b0.y, 0.f);
      af[2] = (_Float16)fmaxf(a0.z + b0.z, 0.f);
      af[3] = (_Float16)fmaxf(a0.w + b0.w, 0.f);
      af[4] = (_Float16)fmaxf(a1.x + b1v.x, 0.f);
      af[5] = (_Float16)fmaxf(a1.y + b1v.y, 0.f);
      af[6] = (_Float16)fmaxf(a1.z + b1v.z, 0.f);
      af[7] = (_Float16)fmaxf(a1.w + b1v.w, 0.f);
      const int kl2 = (ktl*16 + hi*8) * 2;
      #pragma unroll
      for (int nt = 0; nt < 8; ++nt){
        const int n = nt*32 + ln;
        f16x8 bf = *(const f16x8*)((char*)lds + n*128 + (kl2 ^ ((n & 7) << 4)));
        acc[nt] = __builtin_amdgcn_mfma_f32_32x32x16_f16(af, bf, acc[nt], 0, 0, 0);
      }
    }
  }
  __syncthreads();
  // h2 -> LDS [128 pairs][256 ch] f16, XOR-swizzled per pair-row
  #pragma unroll
  for (int nt = 0; nt < 8; ++nt){
    const int ch = nt*32 + ln;
    const float bb = b2[ch];
    #pragma unroll
    for (int r = 0; r < 16; ++r){
      const int pr = wv*32 + (r & 3) + 8*(r >> 2) + 4*hi;
      const float v = fmaxf(acc[nt][r] + bb, 0.f);
      *(_Float16*)((char*)lds + pr*512 + ((ch*2) ^ ((pr & 7) << 4))) = (_Float16)v;
    }
  }
  __syncthreads();
  // logits
  f32x16 acc2[2];
  #pragma unroll
  for (int nt = 0; nt < 2; ++nt){
    #pragma unroll
    for (int e = 0; e < 16; ++e) acc2[nt][e] = 0.f;
  }
  const int pr = wv*32 + ln;
  const int sw2 = (pr & 7) << 4;
  #pragma unroll
  for (int kt = 0; kt < 16; ++kt){
    const int kb = kt*16 + hi*8;
    f16x8 a2 = *(const f16x8*)((char*)lds + pr*512 + ((kb*2) ^ sw2));
    #pragma unroll
    for (int nt = 0; nt < 2; ++nt){
      const int n = nt*32 + ln;
      f16x8 bf = *(const f16x8*)(W3h + n*256 + kb);
      acc2[nt] = __builtin_amdgcn_mfma_f32_32x32x16_f16(a2, bf, acc2[nt], 0, 0, 0);
    }
  }
  // log_softmax over 50 classes
  const float b30 = b3p[ln], b31 = b3p[32 + ln];
  const bool ok2 = (ln < 18);
  #pragma unroll
  for (int qr = 0; qr < 16; ++qr){
    const int r = (qr & 3) + 8*(qr >> 2) + 4*hi;
    float v0 = acc2[0][qr] + b30;
    float v1 = acc2[1][qr] + b31;
    float m = ok2 ? fmaxf(v0, v1) : v0;
    #pragma unroll
    for (int d = 1; d < 32; d <<= 1) m = fmaxf(m, __shfl_xor(m, d));
    float s = __expf(v0 - m) + (ok2 ? __expf(v1 - m) : 0.f);
    #pragma unroll
    for (int d = 1; d < 32; d <<= 1) s += __shfl_xor(s, d);
    const float lse = m + __logf(s);
    const size_t base = ((size_t)(i*512 + jbase + wv*32 + r)) * 50;
    outp[base + ln] = v0 - lse;
    if (ok2) outp[base + 32 + ln] = v1 - lse;
  }
}

// ------------------------------ launch --------------------------------------
extern "C" void kernel_launch(void* const* d_in, const int* in_sizes, int n_in,
                              void* d_out, int out_size, void* d_ws, size_t ws_size,
                              hipStream_t stream)
{
  const float* x     = (const float*)d_in[0];
  const float* Wih_f = (const float*)d_in[1];
  const float* Whh_f = (const float*)d_in[2];
  const float* bih_f = (const float*)d_in[3];
  const float* bhh_f = (const float*)d_in[4];
  const float* Wih_b = (const float*)d_in[5];
  const float* Whh_b = (const float*)d_in[6];
  const float* bih_b = (const float*)d_in[7];
  const float* bhh_b = (const float*)d_in[8];
  const float* W1    = (const float*)d_in[9];
  const float* b1    = (const float*)d_in[10];
  const float* W2    = (const float*)d_in[11];
  const float* b2    = (const float*)d_in[12];
  const float* W3    = (const float*)d_in[13];
  const float* b3    = (const float*)d_in[14];

  char* ws = (char*)d_ws;
  float*    xb     = (float*)(ws + 0);            // 4,194,304
  float*    outcat = (float*)(ws + 4194304);      // 1,048,576
  float*    aP     = (float*)(ws + 5242880);      //   524,288
  float*    bP     = (float*)(ws + 5767168);      //   524,288
  float*    WihT   = (float*)(ws + 6291456);      // 2,457,600
  float*    W1aT   = (float*)(ws + 8749056);      //   524,288
  float*    W1bT   = (float*)(ws + 9273344);      //   524,288
  _Float16* W2h    = (_Float16*)(ws + 9797632);   //   131,072
  _Float16* W3h    = (_Float16*)(ws + 9928704);   //    32,768
  float*    b3p    = (float*)(ws + 9961472);      //       256

  if (ws_size < 9963808) return;   // leaves d_out poisoned -> clean failure

  // lstm needs 136,192 B of dynamic LDS (>64 KB static limit)
  (void)hipFuncSetAttribute((const void*)lstm_kernel,
                            hipFuncAttributeMaxDynamicSharedMemorySize, 136192);

  prep_kernel<<<3745, 256, 0, stream>>>(Wih_f, Wih_b, W1, W2, W3, b3,
                                        WihT, W1aT, W1bT, W2h, W3h, b3p);
  xb_kernel<<<256, 256, 0, stream>>>(x, WihT, bih_f, bhh_f, bih_b, bhh_b, xb);
  lstm_kernel<<<2, 512, 136192, stream>>>(Whh_f, Whh_b, xb, outcat);
  ab_kernel<<<256, 512, 0, stream>>>(outcat, W1aT, W1bT, b1, aP, bP);
  mlp_kernel<<<2048, 256, 0, stream>>>(aP, bP, W2h, W3h, b2, b3p, (float*)d_out);
}

// Round 16
// 952.975 us; speedup vs baseline: 2.6645x; 1.1080x over previous
//
#include <hip/hip_runtime.h>
#include <hip/hip_bf16.h>
#include <hip/hip_fp16.h>
#include <hip/hip_fp8.h>

// ---------------------------------------------------------------------------
// BiLSTM (N=512, D_IN=300, H=256) + pairwise 3-layer MLP (4H->H->H->50)
// + log_softmax, on MI355X.
//
//   lstm (round-16): r15 structure (wave-local gate, 1 barrier/step) with
//   ALL-REGISTER fp8 weights: 8 tiles x 8 k-groups as packed e4m3 in 64 i64
//   regs (128 VGPR -- fits the 2-wave budget; f16 needed 256 and forced 2
//   tiles through LDS). h also e4m3 (fp8_fp8 MFMA needs both operands fp8).
//   Weight-stream DS (16 b128/wave/step, ~47% of DS pipe) is GONE; LDS is
//   4.6 KB static. MFMA rate unchanged (fp8 16x16x32 = f16 rate, m11).
//   A/B use the same k-labeling on both operands -> permutation cancels
//   (same argument HW-verified for f16 in r10).
// ---------------------------------------------------------------------------

typedef _Float16 f16x2 __attribute__((ext_vector_type(2)));
typedef _Float16 f16x8 __attribute__((ext_vector_type(8)));
typedef float    f32x4  __attribute__((ext_vector_type(4)));
typedef float    f32x16 __attribute__((ext_vector_type(16)));
typedef long     i64;

__device__ __forceinline__ float sigf(float x){ return 1.f/(1.f + __expf(-x)); }
__device__ __forceinline__ unsigned char f2q(float v){
  __hip_fp8_e4m3 q(v);
  return (unsigned char)q.__x;
}
__device__ __forceinline__ i64 pack8(const float4 v0, const float4 v1){
  union { unsigned char b[8]; i64 q; } u;
  u.b[0]=f2q(v0.x); u.b[1]=f2q(v0.y); u.b[2]=f2q(v0.z); u.b[3]=f2q(v0.w);
  u.b[4]=f2q(v1.x); u.b[5]=f2q(v1.y); u.b[6]=f2q(v1.z); u.b[7]=f2q(v1.w);
  return u.q;
}

// ------------------------------ prep ---------------------------------------
__global__ __launch_bounds__(256) void prep_kernel(
    const float* __restrict__ Wih_f, const float* __restrict__ Wih_b,
    const float* __restrict__ W1,    const float* __restrict__ W2,
    const float* __restrict__ W3,    const float* __restrict__ b3,
    float* __restrict__ WihT, float* __restrict__ W1aT, float* __restrict__ W1bT,
    _Float16* __restrict__ W2h, _Float16* __restrict__ W3h,
    float* __restrict__ b3p)
{
  int idx = blockIdx.x * 256 + threadIdx.x;
  if (idx < 614400){                     // WihT[d][c][r] = Wih_d[r][c]
    int d = idx / 307200, r2 = idx % 307200;
    int cc = r2 / 1024, rr = r2 % 1024;
    const float* src = d ? Wih_b : Wih_f;
    WihT[idx] = src[rr*300 + cc];
    return;
  }
  idx -= 614400;
  if (idx < 262144){                     // W1aT[c][p]=W1[p][c]; W1bT[c][p]=W1[p][512+c]
    int sel = idx / 131072, r2 = idx % 131072;
    int cc = r2 / 256, pp = r2 % 256;
    float v = W1[pp*1024 + sel*512 + cc];
    (sel ? W1bT : W1aT)[r2] = v;
    return;
  }
  idx -= 262144;
  if (idx < 65536){ W2h[idx] = (_Float16)W2[idx]; return; }
  idx -= 65536;
  if (idx < 16384){                      // W3h padded to [64][256]
    int n = idx >> 8, k = idx & 255;
    W3h[idx] = (n < 50) ? (_Float16)W3[n*256 + k] : (_Float16)0.f;
    return;
  }
  idx -= 16384;
  if (idx < 64){ b3p[idx] = (idx < 50) ? b3[idx] : 0.f; return; }
}

// ------------------------------ xb ------------------------------------------
// Writes PERMUTED layout: xb'[t][unit*4 + gate]  (float4 per unit, coalesced)
__global__ __launch_bounds__(256) void xb_kernel(
    const float* __restrict__ x, const float* __restrict__ WihT,
    const float* __restrict__ bih_f, const float* __restrict__ bhh_f,
    const float* __restrict__ bih_b, const float* __restrict__ bhh_b,
    float* __restrict__ xb)
{
  const int tid = threadIdx.x;
  const int dir = blockIdx.x >> 7;
  const int t0  = (blockIdx.x & 127) * 4;
  __shared__ float xs[4][304];
  #pragma unroll
  for (int tt = 0; tt < 4; ++tt)
    if (tid < 75) ((float4*)xs[tt])[tid] = ((const float4*)(x + (size_t)(t0+tt)*300))[tid];
  __syncthreads();
  const float* W = WihT + dir*307200;
  float acc[4][4];
  #pragma unroll
  for (int r = 0; r < 4; ++r){
    #pragma unroll
    for (int tt = 0; tt < 4; ++tt) acc[r][tt] = 0.f;
  }
  for (int c = 0; c < 300; ++c){
    float x0 = xs[0][c], x1 = xs[1][c], x2 = xs[2][c], x3 = xs[3][c];
    #pragma unroll
    for (int r = 0; r < 4; ++r){
      float wv = W[c*1024 + r*256 + tid];
      acc[r][0] += wv*x0; acc[r][1] += wv*x1; acc[r][2] += wv*x2; acc[r][3] += wv*x3;
    }
  }
  const float* bih = dir ? bih_b : bih_f;
  const float* bhh = dir ? bhh_b : bhh_f;
  float bias[4];
  #pragma unroll
  for (int r = 0; r < 4; ++r) bias[r] = bih[r*256 + tid] + bhh[r*256 + tid];
  float* xbd = xb + (size_t)dir*512*1024;
  #pragma unroll
  for (int tt = 0; tt < 4; ++tt){
    float4 v;
    v.x = acc[0][tt] + bias[0];
    v.y = acc[1][tt] + bias[1];
    v.z = acc[2][tt] + bias[2];
    v.w = acc[3][tt] + bias[3];
    *(float4*)(xbd + (size_t)(t0+tt)*1024 + tid*4) = v;
  }
}

// ------------------------------ lstm ----------------------------------------
#define MFMA8(A, B, C) __builtin_amdgcn_mfma_f32_16x16x32_fp8_fp8((A), (B), (C), 0, 0, 0)

__global__ __launch_bounds__(512)
__attribute__((amdgpu_waves_per_eu(2, 2)))
void lstm_kernel(
    const float* __restrict__ Whh_f, const float* __restrict__ Whh_b,
    const float* __restrict__ xb, float* __restrict__ outcat)
{
  __shared__ float gl[1024];                   // gate results, unit-major
  __shared__ unsigned char hbuf8[2][256];      // h as e4m3, double-buffered

  const int tid = threadIdx.x;
  const int dir = blockIdx.x;
  const int w   = tid >> 6;
  const int l   = tid & 63;
  const int lg  = l >> 4;      // k-group (0..3)
  const int lr  = l & 15;      // row within tile
  const float* Whh = dir ? Whh_b : Whh_f;

  // ---- init: 8 tiles fully register-resident as packed e4m3 (64 i64)
  // tile tt of wave w covers rows' [(w*8+tt)*16, +16) ; row'=unit*4+gate
  i64 wq[64];
  #pragma unroll
  for (int tt = 0; tt < 8; ++tt){
    const int rowp = (w*8 + tt)*16 + lr;
    const int orow = (rowp & 3)*256 + (rowp >> 2);
    const float* src = Whh + (size_t)orow*256 + lg*8;
    #pragma unroll
    for (int c = 0; c < 8; ++c){
      float4 v0 = *(const float4*)(src + c*32);
      float4 v1 = *(const float4*)(src + c*32 + 4);
      wq[tt*8 + c] = pack8(v0, v1);
    }
  }
  if (tid < 128) ((int*)hbuf8)[tid] = 0;       // h_{-1} = 0 (fp8 zero = 0x00)
  __syncthreads();

  const float* xbd = xb + (size_t)dir*512*1024;
  const int u = w*32 + l;                      // this lane's unit (iff l<32)
  float cst = 0.f;

  for (int it = 0; it < 512; ++it){
    const int t = dir ? (511 - it) : it;
    float4 xb4;
    if (l < 32) xb4 = *(const float4*)(xbd + (size_t)t*1024 + u*4);

    // B fragments: h (e4m3) broadcast; lane slot j <- h[c*32 + lg*8 + j]
    const unsigned char* hsrc = hbuf8[it & 1] + lg*8;
    i64 hq[8];
    #pragma unroll
    for (int c = 0; c < 8; ++c) hq[c] = *(const i64*)(hsrc + c*32);

    const bool owner = (lr == 0);
    {
      f32x4 a0 = {0.f,0.f,0.f,0.f}, a1 = {0.f,0.f,0.f,0.f};
      #pragma unroll
      for (int c = 0; c < 8; ++c){
        a0 = MFMA8(wq[0*8+c], hq[c], a0);
        a1 = MFMA8(wq[1*8+c], hq[c], a1);
      }
      if (owner){
        *(f32x4*)(gl + ((w*8+0)*4 + lg)*4) = a0;
        *(f32x4*)(gl + ((w*8+1)*4 + lg)*4) = a1;
      }
    }
    {
      f32x4 a0 = {0.f,0.f,0.f,0.f}, a1 = {0.f,0.f,0.f,0.f};
      #pragma unroll
      for (int c = 0; c < 8; ++c){
        a0 = MFMA8(wq[2*8+c], hq[c], a0);
        a1 = MFMA8(wq[3*8+c], hq[c], a1);
      }
      if (owner){
        *(f32x4*)(gl + ((w*8+2)*4 + lg)*4) = a0;
        *(f32x4*)(gl + ((w*8+3)*4 + lg)*4) = a1;
      }
    }
    {
      f32x4 a0 = {0.f,0.f,0.f,0.f}, a1 = {0.f,0.f,0.f,0.f};
      #pragma unroll
      for (int c = 0; c < 8; ++c){
        a0 = MFMA8(wq[4*8+c], hq[c], a0);
        a1 = MFMA8(wq[5*8+c], hq[c], a1);
      }
      if (owner){
        *(f32x4*)(gl + ((w*8+4)*4 + lg)*4) = a0;
        *(f32x4*)(gl + ((w*8+5)*4 + lg)*4) = a1;
      }
    }
    {
      f32x4 a0 = {0.f,0.f,0.f,0.f}, a1 = {0.f,0.f,0.f,0.f};
      #pragma unroll
      for (int c = 0; c < 8; ++c){
        a0 = MFMA8(wq[6*8+c], hq[c], a0);
        a1 = MFMA8(wq[7*8+c], hq[c], a1);
      }
      if (owner){
        *(f32x4*)(gl + ((w*8+6)*4 + lg)*4) = a0;
        *(f32x4*)(gl + ((w*8+7)*4 + lg)*4) = a1;
      }
    }
    // wave-local gate: lanes l<32 read back THIS wave's gl slice
    // (same-wave LDS write->read, ordered by lgkmcnt -- no barrier)
    if (l < 32){
      f32x4 g4 = *(const f32x4*)(gl + u*4);
      const float gi = g4[0] + xb4.x;
      const float gf = g4[1] + xb4.y;
      const float gg = g4[2] + xb4.z;
      const float go = g4[3] + xb4.w;
      const float iv = sigf(gi);
      const float fv = sigf(gf);
      const float gv = fmaf(sigf(2.f*gg), 2.f, -1.f);    // tanh
      const float ov = sigf(go);
      cst = fmaf(fv, cst, iv*gv);
      const float h = ov * fmaf(sigf(2.f*cst), 2.f, -1.f);
      hbuf8[(it + 1) & 1][u] = f2q(h);
      outcat[(size_t)t*512 + dir*256 + u] = h;
    }
    __syncthreads();    // hbuf8[(it+1)&1] complete; hbuf8[it&1] reads done
  }
}

// ------------------------------ ab ------------------------------------------
// grid 256: block handles 2 sequence positions; thread = (io, sel, q) owns
// outputs p = 2q, 2q+1 of (sel ? bP : aP)[i0+io]. float2 W loads (coalesced).
__global__ __launch_bounds__(512) void ab_kernel(
    const float* __restrict__ outcat, const float* __restrict__ W1aT,
    const float* __restrict__ W1bT,  const float* __restrict__ b1,
    float* __restrict__ aP, float* __restrict__ bP)
{
  __shared__ float orow[2][512];
  const int tid = threadIdx.x;
  const int i0 = blockIdx.x * 2;
  if (tid < 256)
    ((float4*)orow[tid >> 7])[tid & 127] =
        ((const float4*)(outcat + (size_t)(i0 + (tid >> 7))*512))[tid & 127];
  __syncthreads();
  const int io  = tid >> 8;
  const int g   = tid & 255;
  const int sel = g >> 7;
  const int q   = g & 127;
  const int p0  = q * 2;
  const float* W = sel ? W1bT : W1aT;
  const float* xr = orow[io];
  float acc0 = sel ? 0.f : b1[p0];
  float acc1 = sel ? 0.f : b1[p0 + 1];
  #pragma unroll 8
  for (int cc = 0; cc < 512; ++cc){
    const float2 wv = *(const float2*)(W + cc*256 + p0);
    const float xc = xr[cc];
    acc0 = fmaf(wv.x, xc, acc0);
    acc1 = fmaf(wv.y, xc, acc1);
  }
  float2 r; r.x = acc0; r.y = acc1;
  *(float2*)((sel ? bP : aP) + (size_t)(i0 + io)*256 + p0) = r;
}

// ------------------------------ fused MLP -----------------------------------
__global__ __launch_bounds__(256, 2) void mlp_kernel(
    const float* __restrict__ aP, const float* __restrict__ bP,
    const _Float16* __restrict__ W2h, const _Float16* __restrict__ W3h,
    const float* __restrict__ b2, const float* __restrict__ b3p,
    float* __restrict__ outp)
{
  __shared__ _Float16 lds[32768];   // 64KB union: W2 quarter (32KB) / h2 (64KB)
  const int tid = threadIdx.x;
  const int wv  = tid >> 6;
  const int ln  = tid & 31;
  const int hi  = (tid >> 5) & 1;
  const int i     = blockIdx.x >> 2;
  const int jbase = (blockIdx.x & 3) * 128;
  const int j     = jbase + wv*32 + ln;

  f32x16 acc[8];
  #pragma unroll
  for (int nt = 0; nt < 8; ++nt){
    #pragma unroll
    for (int e = 0; e < 16; ++e) acc[nt][e] = 0.f;
  }

  const float* arow = aP + (size_t)i*256;
  const float* brow = bP + (size_t)j*256;

  for (int p = 0; p < 4; ++p){
    if (p) __syncthreads();
    { // stage W2 quarter: rows n=tid, 64 k's, st_16x32 XOR swizzle
      const _Float16* src = W2h + tid*256 + p*64;
      char* dst = (char*)lds + tid*128;
      const int sw = (tid & 7) << 4;
      #pragma unroll
      for (int cc = 0; cc < 8; ++cc){
        f16x8 v = *(const f16x8*)(src + cc*8);
        *(f16x8*)(dst + ((cc*16) ^ sw)) = v;
      }
    }
    __syncthreads();
    #pragma unroll
    for (int ktl = 0; ktl < 4; ++ktl){
      const int kg = (p*4 + ktl)*16 + hi*8;
      float4 a0 = *(const float4*)(arow + kg);
      float4 a1 = *(const float4*)(arow + kg + 4);
      float4 b0 = *(const float4*)(brow + kg);
      float4 b1v = *(const float4*)(brow + kg + 4);
      f16x8 af;
      af[0] = (_Float16)fmaxf(a0.x + b0.x, 0.f);
      af[1] = (_Float16)fmaxf(a0.y + b0.y, 0.f);
      af[2] = (_Float16)fmaxf(a0.z + b0.z, 0.f);
      af[3] = (_Float16)fmaxf(a0.w + b0.w, 0.f);
      af[4] = (_Float16)fmaxf(a1.x + b1v.x, 0.f);
      af[5] = (_Float16)fmaxf(a1.y + b1v.y, 0.f);
      af[6] = (_Float16)fmaxf(a1.z + b1v.z, 0.f);
      af[7] = (_Float16)fmaxf(a1.w + b1v.w, 0.f);
      const int kl2 = (ktl*16 + hi*8) * 2;
      #pragma unroll
      for (int nt = 0; nt < 8; ++nt){
        const int n = nt*32 + ln;
        f16x8 bf = *(const f16x8*)((char*)lds + n*128 + (kl2 ^ ((n & 7) << 4)));
        acc[nt] = __builtin_amdgcn_mfma_f32_32x32x16_f16(af, bf, acc[nt], 0, 0, 0);
      }
    }
  }
  __syncthreads();
  // h2 -> LDS [128 pairs][256 ch] f16, XOR-swizzled per pair-row
  #pragma unroll
  for (int nt = 0; nt < 8; ++nt){
    const int ch = nt*32 + ln;
    const float bb = b2[ch];
    #pragma unroll
    for (int r = 0; r < 16; ++r){
      const int pr = wv*32 + (r & 3) + 8*(r >> 2) + 4*hi;
      const float v = fmaxf(acc[nt][r] + bb, 0.f);
      *(_Float16*)((char*)lds + pr*512 + ((ch*2) ^ ((pr & 7) << 4))) = (_Float16)v;
    }
  }
  __syncthreads();
  // logits
  f32x16 acc2[2];
  #pragma unroll
  for (int nt = 0; nt < 2; ++nt){
    #pragma unroll
    for (int e = 0; e < 16; ++e) acc2[nt][e] = 0.f;
  }
  const int pr = wv*32 + ln;
  const int sw2 = (pr & 7) << 4;
  #pragma unroll
  for (int kt = 0; kt < 16; ++kt){
    const int kb = kt*16 + hi*8;
    f16x8 a2 = *(const f16x8*)((char*)lds + pr*512 + ((kb*2) ^ sw2));
    #pragma unroll
    for (int nt = 0; nt < 2; ++nt){
      const int n = nt*32 + ln;
      f16x8 bf = *(const f16x8*)(W3h + n*256 + kb);
      acc2[nt] = __builtin_amdgcn_mfma_f32_32x32x16_f16(a2, bf, acc2[nt], 0, 0, 0);
    }
  }
  // log_softmax over 50 classes
  const float b30 = b3p[ln], b31 = b3p[32 + ln];
  const bool ok2 = (ln < 18);
  #pragma unroll
  for (int qr = 0; qr < 16; ++qr){
    const int r = (qr & 3) + 8*(qr >> 2) + 4*hi;
    float v0 = acc2[0][qr] + b30;
    float v1 = acc2[1][qr] + b31;
    float m = ok2 ? fmaxf(v0, v1) : v0;
    #pragma unroll
    for (int d = 1; d < 32; d <<= 1) m = fmaxf(m, __shfl_xor(m, d));
    float s = __expf(v0 - m) + (ok2 ? __expf(v1 - m) : 0.f);
    #pragma unroll
    for (int d = 1; d < 32; d <<= 1) s += __shfl_xor(s, d);
    const float lse = m + __logf(s);
    const size_t base = ((size_t)(i*512 + jbase + wv*32 + r)) * 50;
    outp[base + ln] = v0 - lse;
    if (ok2) outp[base + 32 + ln] = v1 - lse;
  }
}

// ------------------------------ launch --------------------------------------
extern "C" void kernel_launch(void* const* d_in, const int* in_sizes, int n_in,
                              void* d_out, int out_size, void* d_ws, size_t ws_size,
                              hipStream_t stream)
{
  const float* x     = (const float*)d_in[0];
  const float* Wih_f = (const float*)d_in[1];
  const float* Whh_f = (const float*)d_in[2];
  const float* bih_f = (const float*)d_in[3];
  const float* bhh_f = (const float*)d_in[4];
  const float* Wih_b = (const float*)d_in[5];
  const float* Whh_b = (const float*)d_in[6];
  const float* bih_b = (const float*)d_in[7];
  const float* bhh_b = (const float*)d_in[8];
  const float* W1    = (const float*)d_in[9];
  const float* b1    = (const float*)d_in[10];
  const float* W2    = (const float*)d_in[11];
  const float* b2    = (const float*)d_in[12];
  const float* W3    = (const float*)d_in[13];
  const float* b3    = (const float*)d_in[14];

  char* ws = (char*)d_ws;
  float*    xb     = (float*)(ws + 0);            // 4,194,304
  float*    outcat = (float*)(ws + 4194304);      // 1,048,576
  float*    aP     = (float*)(ws + 5242880);      //   524,288
  float*    bP     = (float*)(ws + 5767168);      //   524,288
  float*    WihT   = (float*)(ws + 6291456);      // 2,457,600
  float*    W1aT   = (float*)(ws + 8749056);      //   524,288
  float*    W1bT   = (float*)(ws + 9273344);      //   524,288
  _Float16* W2h    = (_Float16*)(ws + 9797632);   //   131,072
  _Float16* W3h    = (_Float16*)(ws + 9928704);   //    32,768
  float*    b3p    = (float*)(ws + 9961472);      //       256

  if (ws_size < 9963808) return;   // leaves d_out poisoned -> clean failure

  prep_kernel<<<3745, 256, 0, stream>>>(Wih_f, Wih_b, W1, W2, W3, b3,
                                        WihT, W1aT, W1bT, W2h, W3h, b3p);
  xb_kernel<<<256, 256, 0, stream>>>(x, WihT, bih_f, bhh_f, bih_b, bhh_b, xb);
  lstm_kernel<<<2, 512, 0, stream>>>(Whh_f, Whh_b, xb, outcat);
  ab_kernel<<<256, 512, 0, stream>>>(outcat, W1aT, W1bT, b1, aP, bP);
  mlp_kernel<<<2048, 256, 0, stream>>>(aP, bP, W2h, W3h, b2, b3p, (float*)d_out);
}

// Round 17
// 786.110 us; speedup vs baseline: 3.2301x; 1.2123x over previous
//
#include <hip/hip_runtime.h>
#include <hip/hip_bf16.h>
#include <hip/hip_fp16.h>
#include <hip/hip_fp8.h>

// ---------------------------------------------------------------------------
// BiLSTM (N=512, D_IN=300, H=256) + pairwise 3-layer MLP (4H->H->H->50)
// + log_softmax, on MI355X.
//
//   lstm (round-17): r16 (all-register fp8 weights, wave-local gate, one
//   barrier/step) with the MFMA upgraded to MX-scaled K=128
//   (mfma_scale_f32_16x16x128_f8f6f4, scales pinned to 1.0 = E8M0 127,
//   exact): 16 MFMAs/wave/step instead of 64. A and B are packed with the
//   SAME k-labeling (lane l: row/col=l&15, k=(l>>4)*32+reg*4+byte) so any
//   internal k-permutation cancels (the argument HW-verified in r10/r16);
//   C/D layout is shape-determined (guide) so owner/gl logic is unchanged.
//   Falls back to the r16 K=32 path if the builtin is absent.
// ---------------------------------------------------------------------------

typedef _Float16 f16x2 __attribute__((ext_vector_type(2)));
typedef _Float16 f16x8 __attribute__((ext_vector_type(8)));
typedef float    f32x4  __attribute__((ext_vector_type(4)));
typedef float    f32x16 __attribute__((ext_vector_type(16)));
typedef int      i32x8  __attribute__((ext_vector_type(8)));
typedef long     i64;

__device__ __forceinline__ float sigf(float x){ return 1.f/(1.f + __expf(-x)); }
__device__ __forceinline__ unsigned char f2q(float v){
  __hip_fp8_e4m3 q(v);
  return (unsigned char)q.__x;
}
__device__ __forceinline__ int pack4(float a, float b, float c, float d){
  union { unsigned char b4[4]; int q; } u;
  u.b4[0]=f2q(a); u.b4[1]=f2q(b); u.b4[2]=f2q(c); u.b4[3]=f2q(d);
  return u.q;
}

// ------------------------------ prep ---------------------------------------
__global__ __launch_bounds__(256) void prep_kernel(
    const float* __restrict__ Wih_f, const float* __restrict__ Wih_b,
    const float* __restrict__ W1,    const float* __restrict__ W2,
    const float* __restrict__ W3,    const float* __restrict__ b3,
    float* __restrict__ WihT, float* __restrict__ W1aT, float* __restrict__ W1bT,
    _Float16* __restrict__ W2h, _Float16* __restrict__ W3h,
    float* __restrict__ b3p)
{
  int idx = blockIdx.x * 256 + threadIdx.x;
  if (idx < 614400){                     // WihT[d][c][r] = Wih_d[r][c]
    int d = idx / 307200, r2 = idx % 307200;
    int cc = r2 / 1024, rr = r2 % 1024;
    const float* src = d ? Wih_b : Wih_f;
    WihT[idx] = src[rr*300 + cc];
    return;
  }
  idx -= 614400;
  if (idx < 262144){                     // W1aT[c][p]=W1[p][c]; W1bT[c][p]=W1[p][512+c]
    int sel = idx / 131072, r2 = idx % 131072;
    int cc = r2 / 256, pp = r2 % 256;
    float v = W1[pp*1024 + sel*512 + cc];
    (sel ? W1bT : W1aT)[r2] = v;
    return;
  }
  idx -= 262144;
  if (idx < 65536){ W2h[idx] = (_Float16)W2[idx]; return; }
  idx -= 65536;
  if (idx < 16384){                      // W3h padded to [64][256]
    int n = idx >> 8, k = idx & 255;
    W3h[idx] = (n < 50) ? (_Float16)W3[n*256 + k] : (_Float16)0.f;
    return;
  }
  idx -= 16384;
  if (idx < 64){ b3p[idx] = (idx < 50) ? b3[idx] : 0.f; return; }
}

// ------------------------------ xb ------------------------------------------
// Writes PERMUTED layout: xb'[t][unit*4 + gate]  (float4 per unit, coalesced)
__global__ __launch_bounds__(256) void xb_kernel(
    const float* __restrict__ x, const float* __restrict__ WihT,
    const float* __restrict__ bih_f, const float* __restrict__ bhh_f,
    const float* __restrict__ bih_b, const float* __restrict__ bhh_b,
    float* __restrict__ xb)
{
  const int tid = threadIdx.x;
  const int dir = blockIdx.x >> 7;
  const int t0  = (blockIdx.x & 127) * 4;
  __shared__ float xs[4][304];
  #pragma unroll
  for (int tt = 0; tt < 4; ++tt)
    if (tid < 75) ((float4*)xs[tt])[tid] = ((const float4*)(x + (size_t)(t0+tt)*300))[tid];
  __syncthreads();
  const float* W = WihT + dir*307200;
  float acc[4][4];
  #pragma unroll
  for (int r = 0; r < 4; ++r){
    #pragma unroll
    for (int tt = 0; tt < 4; ++tt) acc[r][tt] = 0.f;
  }
  for (int c = 0; c < 300; ++c){
    float x0 = xs[0][c], x1 = xs[1][c], x2 = xs[2][c], x3 = xs[3][c];
    #pragma unroll
    for (int r = 0; r < 4; ++r){
      float wv = W[c*1024 + r*256 + tid];
      acc[r][0] += wv*x0; acc[r][1] += wv*x1; acc[r][2] += wv*x2; acc[r][3] += wv*x3;
    }
  }
  const float* bih = dir ? bih_b : bih_f;
  const float* bhh = dir ? bhh_b : bhh_f;
  float bias[4];
  #pragma unroll
  for (int r = 0; r < 4; ++r) bias[r] = bih[r*256 + tid] + bhh[r*256 + tid];
  float* xbd = xb + (size_t)dir*512*1024;
  #pragma unroll
  for (int tt = 0; tt < 4; ++tt){
    float4 v;
    v.x = acc[0][tt] + bias[0];
    v.y = acc[1][tt] + bias[1];
    v.z = acc[2][tt] + bias[2];
    v.w = acc[3][tt] + bias[3];
    *(float4*)(xbd + (size_t)(t0+tt)*1024 + tid*4) = v;
  }
}

// ------------------------------ lstm ----------------------------------------
#if __has_builtin(__builtin_amdgcn_mfma_scale_f32_16x16x128_f8f6f4)
#define HAVE_MX 1
#define MFMAMX(A, B, C) __builtin_amdgcn_mfma_scale_f32_16x16x128_f8f6f4( \
    (A), (B), (C), 0, 0, 0, 127u, 0, 127u)
#else
#define HAVE_MX 0
#endif
#define MFMA8(A, B, C) __builtin_amdgcn_mfma_f32_16x16x32_fp8_fp8((A), (B), (C), 0, 0, 0)

__global__ __launch_bounds__(512)
__attribute__((amdgpu_waves_per_eu(2, 2)))
void lstm_kernel(
    const float* __restrict__ Whh_f, const float* __restrict__ Whh_b,
    const float* __restrict__ xb, float* __restrict__ outcat)
{
  __shared__ float gl[1024];                   // gate results, unit-major
  __shared__ unsigned char hbuf8[2][256];      // h as e4m3, double-buffered

  const int tid = threadIdx.x;
  const int dir = blockIdx.x;
  const int w   = tid >> 6;
  const int l   = tid & 63;
  const int lg  = l >> 4;      // k-group (0..3)
  const int lr  = l & 15;      // row within tile
  const float* Whh = dir ? Whh_b : Whh_f;

#if HAVE_MX
  // ---- 8 tiles x 2 k-halves as K=128 A-frags: lane l holds row l&15,
  // k = (l>>4)*32 + reg*4 + byte (+ half*128). 128 i32 regs total.
  i32x8 wq[16];
  #pragma unroll
  for (int tt = 0; tt < 8; ++tt){
    const int rowp = (w*8 + tt)*16 + lr;
    const int orow = (rowp & 3)*256 + (rowp >> 2);
    #pragma unroll
    for (int hh = 0; hh < 2; ++hh){
      const float* src = Whh + (size_t)orow*256 + hh*128 + lg*32;
      i32x8 o;
      #pragma unroll
      for (int r = 0; r < 8; ++r){
        float4 v = *(const float4*)(src + r*4);
        o[r] = pack4(v.x, v.y, v.z, v.w);
      }
      wq[tt*2 + hh] = o;
    }
  }
#else
  i64 wq[64];
  #pragma unroll
  for (int tt = 0; tt < 8; ++tt){
    const int rowp = (w*8 + tt)*16 + lr;
    const int orow = (rowp & 3)*256 + (rowp >> 2);
    const float* src = Whh + (size_t)orow*256 + lg*8;
    #pragma unroll
    for (int c = 0; c < 8; ++c){
      float4 v0 = *(const float4*)(src + c*32);
      float4 v1 = *(const float4*)(src + c*32 + 4);
      union { int i2[2]; i64 q; } u;
      u.i2[0] = pack4(v0.x, v0.y, v0.z, v0.w);
      u.i2[1] = pack4(v1.x, v1.y, v1.z, v1.w);
      wq[tt*8 + c] = u.q;
    }
  }
#endif
  if (tid < 128) ((int*)hbuf8)[tid] = 0;       // h_{-1} = 0 (fp8 zero = 0x00)
  __syncthreads();

  const float* xbd = xb + (size_t)dir*512*1024;
  const int u = w*32 + l;                      // this lane's unit (iff l<32)
  float cst = 0.f;

  for (int it = 0; it < 512; ++it){
    const int t = dir ? (511 - it) : it;
    float4 xb4;
    if (l < 32) xb4 = *(const float4*)(xbd + (size_t)t*1024 + u*4);

    const bool owner = (lr == 0);

#if HAVE_MX
    // B frags: h (e4m3) broadcast; lane l holds k=(l>>4)*32+reg*4+byte (+half*128)
    i32x8 hq0, hq1;
    __builtin_memcpy(&hq0, hbuf8[it & 1] + lg*32, 32);
    __builtin_memcpy(&hq1, hbuf8[it & 1] + 128 + lg*32, 32);
    #pragma unroll
    for (int g2 = 0; g2 < 4; ++g2){
      f32x4 a0 = {0.f,0.f,0.f,0.f}, a1 = {0.f,0.f,0.f,0.f};
      a0 = MFMAMX(wq[(g2*2+0)*2+0], hq0, a0);
      a1 = MFMAMX(wq[(g2*2+1)*2+0], hq0, a1);
      a0 = MFMAMX(wq[(g2*2+0)*2+1], hq1, a0);
      a1 = MFMAMX(wq[(g2*2+1)*2+1], hq1, a1);
      if (owner){
        *(f32x4*)(gl + ((w*8 + g2*2+0)*4 + lg)*4) = a0;
        *(f32x4*)(gl + ((w*8 + g2*2+1)*4 + lg)*4) = a1;
      }
    }
#else
    const unsigned char* hsrc = hbuf8[it & 1] + lg*8;
    i64 hq[8];
    #pragma unroll
    for (int c = 0; c < 8; ++c) hq[c] = *(const i64*)(hsrc + c*32);
    #pragma unroll
    for (int g2 = 0; g2 < 4; ++g2){
      f32x4 a0 = {0.f,0.f,0.f,0.f}, a1 = {0.f,0.f,0.f,0.f};
      #pragma unroll
      for (int c = 0; c < 8; ++c){
        a0 = MFMA8(wq[(g2*2+0)*8+c], hq[c], a0);
        a1 = MFMA8(wq[(g2*2+1)*8+c], hq[c], a1);
      }
      if (owner){
        *(f32x4*)(gl + ((w*8 + g2*2+0)*4 + lg)*4) = a0;
        *(f32x4*)(gl + ((w*8 + g2*2+1)*4 + lg)*4) = a1;
      }
    }
#endif
    // wave-local gate: lanes l<32 read back THIS wave's gl slice
    // (same-wave LDS write->read, ordered by lgkmcnt -- no barrier)
    if (l < 32){
      f32x4 g4 = *(const f32x4*)(gl + u*4);
      const float gi = g4[0] + xb4.x;
      const float gf = g4[1] + xb4.y;
      const float gg = g4[2] + xb4.z;
      const float go = g4[3] + xb4.w;
      const float iv = sigf(gi);
      const float fv = sigf(gf);
      const float gv = fmaf(sigf(2.f*gg), 2.f, -1.f);    // tanh
      const float ov = sigf(go);
      cst = fmaf(fv, cst, iv*gv);
      const float h = ov * fmaf(sigf(2.f*cst), 2.f, -1.f);
      hbuf8[(it + 1) & 1][u] = f2q(h);
      outcat[(size_t)t*512 + dir*256 + u] = h;
    }
    __syncthreads();    // hbuf8[(it+1)&1] complete; hbuf8[it&1] reads done
  }
}

// ------------------------------ ab ------------------------------------------
// grid 256: block handles 2 sequence positions; thread = (io, sel, q) owns
// outputs p = 2q, 2q+1 of (sel ? bP : aP)[i0+io]. float2 W loads (coalesced).
__global__ __launch_bounds__(512) void ab_kernel(
    const float* __restrict__ outcat, const float* __restrict__ W1aT,
    const float* __restrict__ W1bT,  const float* __restrict__ b1,
    float* __restrict__ aP, float* __restrict__ bP)
{
  __shared__ float orow[2][512];
  const int tid = threadIdx.x;
  const int i0 = blockIdx.x * 2;
  if (tid < 256)
    ((float4*)orow[tid >> 7])[tid & 127] =
        ((const float4*)(outcat + (size_t)(i0 + (tid >> 7))*512))[tid & 127];
  __syncthreads();
  const int io  = tid >> 8;
  const int g   = tid & 255;
  const int sel = g >> 7;
  const int q   = g & 127;
  const int p0  = q * 2;
  const float* W = sel ? W1bT : W1aT;
  const float* xr = orow[io];
  float acc0 = sel ? 0.f : b1[p0];
  float acc1 = sel ? 0.f : b1[p0 + 1];
  #pragma unroll 8
  for (int cc = 0; cc < 512; ++cc){
    const float2 wv = *(const float2*)(W + cc*256 + p0);
    const float xc = xr[cc];
    acc0 = fmaf(wv.x, xc, acc0);
    acc1 = fmaf(wv.y, xc, acc1);
  }
  float2 r; r.x = acc0; r.y = acc1;
  *(float2*)((sel ? bP : aP) + (size_t)(i0 + io)*256 + p0) = r;
}

// ------------------------------ fused MLP -----------------------------------
__global__ __launch_bounds__(256, 2) void mlp_kernel(
    const float* __restrict__ aP, const float* __restrict__ bP,
    const _Float16* __restrict__ W2h, const _Float16* __restrict__ W3h,
    const float* __restrict__ b2, const float* __restrict__ b3p,
    float* __restrict__ outp)
{
  __shared__ _Float16 lds[32768];   // 64KB union: W2 quarter (32KB) / h2 (64KB)
  const int tid = threadIdx.x;
  const int wv  = tid >> 6;
  const int ln  = tid & 31;
  const int hi  = (tid >> 5) & 1;
  const int i     = blockIdx.x >> 2;
  const int jbase = (blockIdx.x & 3) * 128;
  const int j     = jbase + wv*32 + ln;

  f32x16 acc[8];
  #pragma unroll
  for (int nt = 0; nt < 8; ++nt){
    #pragma unroll
    for (int e = 0; e < 16; ++e) acc[nt][e] = 0.f;
  }

  const float* arow = aP + (size_t)i*256;
  const float* brow = bP + (size_t)j*256;

  for (int p = 0; p < 4; ++p){
    if (p) __syncthreads();
    { // stage W2 quarter: rows n=tid, 64 k's, st_16x32 XOR swizzle
      const _Float16* src = W2h + tid*256 + p*64;
      char* dst = (char*)lds + tid*128;
      const int sw = (tid & 7) << 4;
      #pragma unroll
      for (int cc = 0; cc < 8; ++cc){
        f16x8 v = *(const f16x8*)(src + cc*8);
        *(f16x8*)(dst + ((cc*16) ^ sw)) = v;
      }
    }
    __syncthreads();
    #pragma unroll
    for (int ktl = 0; ktl < 4; ++ktl){
      const int kg = (p*4 + ktl)*16 + hi*8;
      float4 a0 = *(const float4*)(arow + kg);
      float4 a1 = *(const float4*)(arow + kg + 4);
      float4 b0 = *(const float4*)(brow + kg);
      float4 b1v = *(const float4*)(brow + kg + 4);
      f16x8 af;
      af[0] = (_Float16)fmaxf(a0.x + b0.x, 0.f);
      af[1] = (_Float16)fmaxf(a0.y + b0.y, 0.f);
      af[2] = (_Float16)fmaxf(a0.z + b0.z, 0.f);
      af[3] = (_Float16)fmaxf(a0.w + b0.w, 0.f);
      af[4] = (_Float16)fmaxf(a1.x + b1v.x, 0.f);
      af[5] = (_Float16)fmaxf(a1.y + b1v.y, 0.f);
      af[6] = (_Float16)fmaxf(a1.z + b1v.z, 0.f);
      af[7] = (_Float16)fmaxf(a1.w + b1v.w, 0.f);
      const int kl2 = (ktl*16 + hi*8) * 2;
      #pragma unroll
      for (int nt = 0; nt < 8; ++nt){
        const int n = nt*32 + ln;
        f16x8 bf = *(const f16x8*)((char*)lds + n*128 + (kl2 ^ ((n & 7) << 4)));
        acc[nt] = __builtin_amdgcn_mfma_f32_32x32x16_f16(af, bf, acc[nt], 0, 0, 0);
      }
    }
  }
  __syncthreads();
  // h2 -> LDS [128 pairs][256 ch] f16, XOR-swizzled per pair-row
  #pragma unroll
  for (int nt = 0; nt < 8; ++nt){
    const int ch = nt*32 + ln;
    const float bb = b2[ch];
    #pragma unroll
    for (int r = 0; r < 16; ++r){
      const int pr = wv*32 + (r & 3) + 8*(r >> 2) + 4*hi;
      const float v = fmaxf(acc[nt][r] + bb, 0.f);
      *(_Float16*)((char*)lds + pr*512 + ((ch*2) ^ ((pr & 7) << 4))) = (_Float16)v;
    }
  }
  __syncthreads();
  // logits
  f32x16 acc2[2];
  #pragma unroll
  for (int nt = 0; nt < 2; ++nt){
    #pragma unroll
    for (int e = 0; e < 16; ++e) acc2[nt][e] = 0.f;
  }
  const int pr = wv*32 + ln;
  const int sw2 = (pr & 7) << 4;
  #pragma unroll
  for (int kt = 0; kt < 16; ++kt){
    const int kb = kt*16 + hi*8;
    f16x8 a2 = *(const f16x8*)((char*)lds + pr*512 + ((kb*2) ^ sw2));
    #pragma unroll
    for (int nt = 0; nt < 2; ++nt){
      const int n = nt*32 + ln;
      f16x8 bf = *(const f16x8*)(W3h + n*256 + kb);
      acc2[nt] = __builtin_amdgcn_mfma_f32_32x32x16_f16(a2, bf, acc2[nt], 0, 0, 0);
    }
  }
  // log_softmax over 50 classes
  const float b30 = b3p[ln], b31 = b3p[32 + ln];
  const bool ok2 = (ln < 18);
  #pragma unroll
  for (int qr = 0; qr < 16; ++qr){
    const int r = (qr & 3) + 8*(qr >> 2) + 4*hi;
    float v0 = acc2[0][qr] + b30;
    float v1 = acc2[1][qr] + b31;
    float m = ok2 ? fmaxf(v0, v1) : v0;
    #pragma unroll
    for (int d = 1; d < 32; d <<= 1) m = fmaxf(m, __shfl_xor(m, d));
    float s = __expf(v0 - m) + (ok2 ? __expf(v1 - m) : 0.f);
    #pragma unroll
    for (int d = 1; d < 32; d <<= 1) s += __shfl_xor(s, d);
    const float lse = m + __logf(s);
    const size_t base = ((size_t)(i*512 + jbase + wv*32 + r)) * 50;
    outp[base + ln] = v0 - lse;
    if (ok2) outp[base + 32 + ln] = v1 - lse;
  }
}

// ------------------------------ launch --------------------------------------
extern "C" void kernel_launch(void* const* d_in, const int* in_sizes, int n_in,
                              void* d_out, int out_size, void* d_ws, size_t ws_size,
                              hipStream_t stream)
{
  const float* x     = (const float*)d_in[0];
  const float* Wih_f = (const float*)d_in[1];
  const float* Whh_f = (const float*)d_in[2];
  const float* bih_f = (const float*)d_in[3];
  const float* bhh_f = (const float*)d_in[4];
  const float* Wih_b = (const float*)d_in[5];
  const float* Whh_b = (const float*)d_in[6];
  const float* bih_b = (const float*)d_in[7];
  const float* bhh_b = (const float*)d_in[8];
  const float* W1    = (const float*)d_in[9];
  const float* b1    = (const float*)d_in[10];
  const float* W2    = (const float*)d_in[11];
  const float* b2    = (const float*)d_in[12];
  const float* W3    = (const float*)d_in[13];
  const float* b3    = (const float*)d_in[14];

  char* ws = (char*)d_ws;
  float*    xb     = (float*)(ws + 0);            // 4,194,304
  float*    outcat = (float*)(ws + 4194304);      // 1,048,576
  float*    aP     = (float*)(ws + 5242880);      //   524,288
  float*    bP     = (float*)(ws + 5767168);      //   524,288
  float*    WihT   = (float*)(ws + 6291456);      // 2,457,600
  float*    W1aT   = (float*)(ws + 8749056);      //   524,288
  float*    W1bT   = (float*)(ws + 9273344);      //   524,288
  _Float16* W2h    = (_Float16*)(ws + 9797632);   //   131,072
  _Float16* W3h    = (_Float16*)(ws + 9928704);   //    32,768
  float*    b3p    = (float*)(ws + 9961472);      //       256

  if (ws_size < 9963808) return;   // leaves d_out poisoned -> clean failure

  prep_kernel<<<3745, 256, 0, stream>>>(Wih_f, Wih_b, W1, W2, W3, b3,
                                        WihT, W1aT, W1bT, W2h, W3h, b3p);
  xb_kernel<<<256, 256, 0, stream>>>(x, WihT, bih_f, bhh_f, bih_b, bhh_b, xb);
  lstm_kernel<<<2, 512, 0, stream>>>(Whh_f, Whh_b, xb, outcat);
  ab_kernel<<<256, 512, 0, stream>>>(outcat, W1aT, W1bT, b1, aP, bP);
  mlp_kernel<<<2048, 256, 0, stream>>>(aP, bP, W2h, W3h, b2, b3p, (float*)d_out);
}